// Round 1
// baseline (6471.547 us; speedup 1.0000x reference)
//
#include <hip/hip_runtime.h>
#include <math.h>

#define TFRAMES 4096
#define DM 128
#define LQ 64
#define NG 16
#define NH 8
#define DQH 16
#define FD 2048
#define GFD 512
#define PAD 63
#define KVROWS (TFRAMES + PAD)      /* 4159 */
#define ASTRIDE (KVROWS * DM)       /* 532352 floats per K/V array */
#define SCP 65                      /* padded score row stride (bank-conflict fix) */

/* ws layout (floats) */
#define OFF_VISN 0
#define OFF_KV   (TFRAMES * DM)                  /* 524288 */
#define OFF_TEXT (OFF_KV + 4 * ASTRIDE)          /* 2653696 */
#define OFF_KF   (OFF_TEXT + NG * DM)
#define OFF_VF   (OFF_KF + NG * DM)

// ---------------- kernel 1: visual = lf @ W_vis ; visn = LN(visual) ----------
__global__ __launch_bounds__(128) void k_visln(const float* __restrict__ lf,
                                               const float* __restrict__ Wvis,
                                               float* __restrict__ visn) {
    __shared__ float xs[16][256];
    __shared__ float vis[16][128];
    __shared__ float part[16][8][2];
    __shared__ float mean_s[16], rstd_s[16];
    const int tid = threadIdx.x;          // 128 threads: one output column each
    const int r0 = blockIdx.x * 16;
    float acc[16];
#pragma unroll
    for (int r = 0; r < 16; ++r) acc[r] = 0.f;
    for (int c = 0; c < 8; ++c) {         // K chunks of 256
        const int k0 = c * 256;
        for (int idx = tid; idx < 16 * 256; idx += 128) {
            int r = idx >> 8, kk = idx & 255;
            xs[r][kk] = lf[(size_t)(r0 + r) * FD + k0 + kk];
        }
        __syncthreads();
        for (int k4 = 0; k4 < 64; ++k4) {
            const float* wp = Wvis + (size_t)(k0 + k4 * 4) * DM + tid;
            float w0 = wp[0 * DM], w1 = wp[1 * DM], w2 = wp[2 * DM], w3 = wp[3 * DM];
#pragma unroll
            for (int r = 0; r < 16; ++r) {
                const float4 x4 = *(const float4*)&xs[r][k4 * 4];
                acc[r] += x4.x * w0 + x4.y * w1 + x4.z * w2 + x4.w * w3;
            }
        }
        __syncthreads();
    }
#pragma unroll
    for (int r = 0; r < 16; ++r) vis[r][tid] = acc[r];
    __syncthreads();
    {   // LN over the 128 columns of each of the 16 rows
        int r = tid >> 3, p = tid & 7;
        float s = 0.f, s2 = 0.f;
#pragma unroll
        for (int k = 0; k < 16; ++k) { float v = vis[r][p * 16 + k]; s += v; s2 += v * v; }
        part[r][p][0] = s; part[r][p][1] = s2;
    }
    __syncthreads();
    if (tid < 16) {
        float s = 0.f, s2 = 0.f;
#pragma unroll
        for (int p = 0; p < 8; ++p) { s += part[tid][p][0]; s2 += part[tid][p][1]; }
        float m = s * (1.f / 128.f);
        float v = s2 * (1.f / 128.f) - m * m;
        mean_s[tid] = m; rstd_s[tid] = rsqrtf(v + 1e-5f);
    }
    __syncthreads();
#pragma unroll
    for (int r = 0; r < 16; ++r)
        visn[(size_t)(r0 + r) * DM + tid] = (vis[r][tid] - mean_s[r]) * rstd_s[r];
}

// ---------------- kernel 2: K_l / V_l = visn @ Wk_enc[l] / Wv_enc[l] ---------
__global__ __launch_bounds__(128) void k_kvproj(const float* __restrict__ visn,
                                                const float* __restrict__ Wk_enc,
                                                const float* __restrict__ Wv_enc,
                                                float* __restrict__ kv) {
    __shared__ float xs[16][128];
    const int tid = threadIdx.x;
    const int r0 = blockIdx.x * 16;
    const int a = blockIdx.y;             // 0:l0K 1:l0V 2:l1K 3:l1V
    const float* W = ((a & 1) ? Wv_enc : Wk_enc) + (size_t)(a >> 1) * DM * DM;
    float* out = kv + (size_t)a * ASTRIDE;
    for (int idx = tid; idx < 16 * 128; idx += 128)
        xs[idx >> 7][idx & 127] = visn[(size_t)r0 * DM + idx];
    __syncthreads();
    float acc[16];
#pragma unroll
    for (int r = 0; r < 16; ++r) acc[r] = 0.f;
    for (int k4 = 0; k4 < 32; ++k4) {
        const float* wp = W + (size_t)(k4 * 4) * DM + tid;
        float w0 = wp[0 * DM], w1 = wp[1 * DM], w2 = wp[2 * DM], w3 = wp[3 * DM];
#pragma unroll
        for (int r = 0; r < 16; ++r) {
            const float4 x4 = *(const float4*)&xs[r][k4 * 4];
            acc[r] += x4.x * w0 + x4.y * w1 + x4.z * w2 + x4.w * w3;
        }
    }
#pragma unroll
    for (int r = 0; r < 16; ++r)
        out[(size_t)(PAD + r0 + r) * DM + tid] = acc[r];
}

// -------- kernel 3: text = g @ W_txt ; Kf = text @ Wk_f ; Vf = text @ Wv_f ---
__global__ __launch_bounds__(128) void k_text(const float* __restrict__ g,
                                              const float* __restrict__ Wtxt,
                                              const float* __restrict__ Wkf,
                                              const float* __restrict__ Wvf,
                                              float* __restrict__ text,
                                              float* __restrict__ kf,
                                              float* __restrict__ vf) {
    __shared__ float gs[GFD];
    __shared__ float tr[DM];
    const int r = blockIdx.x;            // gesture row, 16 blocks
    const int tid = threadIdx.x;         // 128
    for (int i = tid; i < GFD; i += 128) gs[i] = g[(size_t)r * GFD + i];
    __syncthreads();
    float acc = 0.f;
    for (int k = 0; k < GFD; ++k) acc += gs[k] * Wtxt[(size_t)k * DM + tid];
    tr[tid] = acc;
    text[(size_t)r * DM + tid] = acc;
    __syncthreads();
    float a1 = 0.f, a2 = 0.f;
    for (int k = 0; k < DM; ++k) {
        float x = tr[k];
        a1 += x * Wkf[(size_t)k * DM + tid];
        a2 += x * Wvf[(size_t)k * DM + tid];
    }
    kf[(size_t)r * DM + tid] = a1;
    vf[(size_t)r * DM + tid] = a2;
}

// ---------------- LN helper for a [16][128] LDS tile -------------------------
__device__ __forceinline__ void ln16x128(const float* __restrict__ src,
                                         float* __restrict__ dst,
                                         float* part2, float* mean_s, float* rstd_s,
                                         int tid) {
    if (tid < 128) {
        int r = tid >> 3, p = tid & 7;
        const float* row = src + r * 128 + p * 16;
        float s = 0.f, s2 = 0.f;
#pragma unroll
        for (int k = 0; k < 16; ++k) { float v = row[k]; s += v; s2 += v * v; }
        part2[tid * 2] = s; part2[tid * 2 + 1] = s2;
    }
    __syncthreads();
    if (tid < 16) {
        float s = 0.f, s2 = 0.f;
#pragma unroll
        for (int p = 0; p < 8; ++p) { s += part2[(tid * 8 + p) * 2]; s2 += part2[(tid * 8 + p) * 2 + 1]; }
        float m = s * (1.f / 128.f);
        float v = s2 * (1.f / 128.f) - m * m;
        mean_s[tid] = m; rstd_s[tid] = rsqrtf(v + 1e-5f);
    }
    __syncthreads();
    for (int o = tid; o < 2048; o += 512) {
        int r = o >> 7;
        dst[o] = (src[o] - mean_s[r]) * rstd_s[r];
    }
    __syncthreads();
}

// ---------------- kernel 4: per-frame encoder + final attention --------------
__global__ __launch_bounds__(512) void k_frames(
    const float* __restrict__ Wq_enc, const float* __restrict__ W1f,
    const float* __restrict__ W2f,    const float* __restrict__ Wqf,
    const float* __restrict__ kv,     const float* __restrict__ text,
    const float* __restrict__ kf,     const float* __restrict__ vf,
    float* __restrict__ out) {
    __shared__ float t_cur[16][128];
    __shared__ float tqs[16][128];
    __shared__ float qb[16][128];
    __shared__ float sc[128 * SCP];   // scores [128 grp][64+pad]; FFN h-chunk [16][512] flat
    __shared__ float part2[256];
    __shared__ float mean_s[16], rstd_s[16];

    const int tid = threadIdx.x;       // 512
    const int T = blockIdx.x;          // frame
    const int j = tid & 127;           // column for 2048-wide loops
    const int r0 = tid >> 7;           // 0..3 ; rows r0, r0+4, r0+8, r0+12

    for (int o = tid; o < 2048; o += 512) (&t_cur[0][0])[o] = text[o];
    __syncthreads();

    for (int l = 0; l < 2; ++l) {
        // tq = LN(t)
        ln16x128(&t_cur[0][0], &tqs[0][0], part2, mean_s, rstd_s, tid);
        // Q = tq @ Wq_enc[l] -> qb
        {
            const float* Wq = Wq_enc + (size_t)l * DM * DM;
            float acc[4] = {0.f, 0.f, 0.f, 0.f};
#pragma unroll 4
            for (int k = 0; k < DM; ++k) {
                float w = Wq[(size_t)k * DM + j];
#pragma unroll
                for (int rr = 0; rr < 4; ++rr) acc[rr] += tqs[r0 + 4 * rr][k] * w;
            }
#pragma unroll
            for (int rr = 0; rr < 4; ++rr) qb[r0 + 4 * rr][j] = acc[rr];
        }
        __syncthreads();
        // scores: [h][q][k] = Q . K_window / 4   (window row = padded row T+k)
        {
            const float* Kl = kv + (size_t)(2 * l) * ASTRIDE;
#pragma unroll
            for (int i = 0; i < 16; ++i) {
                int s = tid + 512 * i;            // 8192 scores
                int k = s & 63, gidx = s >> 6;    // gidx = h*16 + q
                int h = gidx >> 4, r = gidx & 15;
                const float* krow = Kl + (size_t)(T + k) * DM + h * DQH;
                const float* qrow = &qb[r][h * DQH];
                float acc = 0.f;
#pragma unroll
                for (int d = 0; d < 16; ++d) acc += qrow[d] * krow[d];
                sc[gidx * SCP + k] = acc * 0.25f;
            }
        }
        __syncthreads();
        // softmax over k per (h,q) group
        if (tid < 128) {
            float* row = sc + tid * SCP;
            float mx = row[0];
            for (int k = 1; k < 64; ++k) mx = fmaxf(mx, row[k]);
            float sum = 0.f;
            for (int k = 0; k < 64; ++k) { float e = expf(row[k] - mx); row[k] = e; sum += e; }
            float inv = 1.f / sum;
            for (int k = 0; k < 64; ++k) row[k] *= inv;
        }
        __syncthreads();
        // ctx = attn @ V_window ; + residual tq -> qb
        {
            const float* Vl = kv + (size_t)(2 * l + 1) * ASTRIDE;
            const int h = j >> 4;
            float acc[4] = {0.f, 0.f, 0.f, 0.f};
#pragma unroll 4
            for (int k = 0; k < 64; ++k) {
                float v = Vl[(size_t)(T + k) * DM + j];
#pragma unroll
                for (int rr = 0; rr < 4; ++rr)
                    acc[rr] += sc[(h * 16 + r0 + 4 * rr) * SCP + k] * v;
            }
#pragma unroll
            for (int rr = 0; rr < 4; ++rr)
                qb[r0 + 4 * rr][j] = acc[rr] + tqs[r0 + 4 * rr][j];
        }
        __syncthreads();
        // t = LN(ctx + tq)
        ln16x128(&qb[0][0], &t_cur[0][0], part2, mean_s, rstd_s, tid);
        // x = LN(t) -> tqs
        ln16x128(&t_cur[0][0], &tqs[0][0], part2, mean_s, rstd_s, tid);
        // FFN: y = relu(x@W1)@W2 ; t = LN(y + x)
        {
            const float* w1 = W1f + (size_t)l * DM * FD;
            const float* w2 = W2f + (size_t)l * FD * DM;
            float yacc[4] = {0.f, 0.f, 0.f, 0.f};
            for (int c = 0; c < 4; ++c) {
                // h[r][tid] over all 16 rows for this thread's column (c*512+tid)
                float hacc[16];
#pragma unroll
                for (int r = 0; r < 16; ++r) hacc[r] = 0.f;
                for (int k4 = 0; k4 < 32; ++k4) {
                    const float* wp = w1 + (size_t)(k4 * 4) * FD + c * 512 + tid;
                    float w0 = wp[0 * FD], w1v = wp[1 * FD], w2v = wp[2 * FD], w3v = wp[3 * FD];
#pragma unroll
                    for (int r = 0; r < 16; ++r) {
                        const float4 x4 = *(const float4*)&tqs[r][k4 * 4];
                        hacc[r] += x4.x * w0 + x4.y * w1v + x4.z * w2v + x4.w * w3v;
                    }
                }
                __syncthreads();   // prior chunk's sc consumers done before overwrite
#pragma unroll
                for (int r = 0; r < 16; ++r) sc[r * 512 + tid] = fmaxf(hacc[r], 0.f);
                __syncthreads();
                // y += h_chunk @ W2_chunk
                for (int jj4 = 0; jj4 < 128; ++jj4) {
                    const float* wp = w2 + (size_t)(c * 512 + jj4 * 4) * DM + j;
                    float w0 = wp[0 * DM], w1v = wp[1 * DM], w2v = wp[2 * DM], w3v = wp[3 * DM];
#pragma unroll
                    for (int rr = 0; rr < 4; ++rr) {
                        const float4 h4 = *(const float4*)&sc[(r0 + 4 * rr) * 512 + jj4 * 4];
                        yacc[rr] += h4.x * w0 + h4.y * w1v + h4.z * w2v + h4.w * w3v;
                    }
                }
            }
            __syncthreads();
#pragma unroll
            for (int rr = 0; rr < 4; ++rr)
                qb[r0 + 4 * rr][j] = yacc[rr] + tqs[r0 + 4 * rr][j];
        }
        __syncthreads();
        ln16x128(&qb[0][0], &t_cur[0][0], part2, mean_s, rstd_s, tid);
    }

    // ---- final single-head attention: Q = t@Wq_f, K/V precomputed ----
    {
        float acc[4] = {0.f, 0.f, 0.f, 0.f};
#pragma unroll 4
        for (int k = 0; k < DM; ++k) {
            float w = Wqf[(size_t)k * DM + j];
#pragma unroll
            for (int rr = 0; rr < 4; ++rr) acc[rr] += t_cur[r0 + 4 * rr][k] * w;
        }
#pragma unroll
        for (int rr = 0; rr < 4; ++rr) tqs[r0 + 4 * rr][j] = acc[rr];
    }
    __syncthreads();
    if (tid < 256) {
        int qr = tid >> 4, kr = tid & 15;
        float acc = 0.f;
#pragma unroll 4
        for (int d = 0; d < DM; ++d) acc += tqs[qr][d] * kf[(size_t)kr * DM + d];
        sc[tid] = acc * 0.08838834764831845f;   // 1/sqrt(128)
    }
    __syncthreads();
    if (tid < 16) {
        float* row = sc + tid * 16;
        float mx = row[0];
        for (int k = 1; k < 16; ++k) mx = fmaxf(mx, row[k]);
        float sum = 0.f;
        for (int k = 0; k < 16; ++k) { float e = expf(row[k] - mx); row[k] = e; sum += e; }
        float inv = 1.f / sum;
        for (int k = 0; k < 16; ++k) row[k] *= inv;
    }
    __syncthreads();
    {
        float acc[4] = {0.f, 0.f, 0.f, 0.f};
#pragma unroll
        for (int k = 0; k < 16; ++k) {
            float v = vf[(size_t)k * DM + j];
#pragma unroll
            for (int rr = 0; rr < 4; ++rr) acc[rr] += sc[(r0 + 4 * rr) * 16 + k] * v;
        }
#pragma unroll
        for (int rr = 0; rr < 4; ++rr)
            qb[r0 + 4 * rr][j] = acc[rr] + t_cur[r0 + 4 * rr][j];
    }
    __syncthreads();
    ln16x128(&qb[0][0], &tqs[0][0], part2, mean_s, rstd_s, tid);
    for (int o = tid; o < 2048; o += 512)
        out[(size_t)T * 2048 + o] = (&tqs[0][0])[o];
}

extern "C" void kernel_launch(void* const* d_in, const int* in_sizes, int n_in,
                              void* d_out, int out_size, void* d_ws, size_t ws_size,
                              hipStream_t stream) {
    const float* g      = (const float*)d_in[0];
    const float* lf     = (const float*)d_in[1];
    const float* Wvis   = (const float*)d_in[2];
    const float* Wtxt   = (const float*)d_in[3];
    const float* Wq_enc = (const float*)d_in[4];
    const float* Wk_enc = (const float*)d_in[5];
    const float* Wv_enc = (const float*)d_in[6];
    const float* W1f    = (const float*)d_in[7];
    const float* W2f    = (const float*)d_in[8];
    const float* Wqf    = (const float*)d_in[9];
    const float* Wkf    = (const float*)d_in[10];
    const float* Wvf    = (const float*)d_in[11];
    float* out = (float*)d_out;
    float* ws  = (float*)d_ws;

    float* visn = ws + OFF_VISN;
    float* kv   = ws + OFF_KV;
    float* text = ws + OFF_TEXT;
    float* kfp  = ws + OFF_KF;
    float* vfp  = ws + OFF_VF;

    // zero the 63 padding rows at the head of each K/V array (ws is poisoned)
    for (int a = 0; a < 4; ++a)
        hipMemsetAsync(kv + (size_t)a * ASTRIDE, 0, (size_t)PAD * DM * sizeof(float), stream);

    k_visln <<<dim3(TFRAMES / 16), dim3(128), 0, stream>>>(lf, Wvis, visn);
    k_kvproj<<<dim3(TFRAMES / 16, 4), dim3(128), 0, stream>>>(visn, Wk_enc, Wv_enc, kv);
    k_text  <<<dim3(NG), dim3(128), 0, stream>>>(g, Wtxt, Wkf, Wvf, text, kfp, vfp);
    k_frames<<<dim3(TFRAMES), dim3(512), 0, stream>>>(Wq_enc, W1f, W2f, Wqf, kv, text, kfp, vfp, out);
}

// Round 2
// 1994.498 us; speedup vs baseline: 3.2447x; 3.2447x over previous
//
#include <hip/hip_runtime.h>
#include <math.h>

#define TFRAMES 4096
#define DM 128
#define LQ 64
#define NG 16
#define NH 8
#define DQH 16
#define FD 2048
#define GFD 512
#define PAD 63
#define KVROWS (TFRAMES + PAD)      /* 4159 */
#define ASTRIDE (KVROWS * DM)       /* 532352 floats per K/V array */
#define SCP 65                      /* padded score row stride (bank-conflict fix) */

/* ws layout (floats) */
#define OFF_VISN 0
#define OFF_KV   (TFRAMES * DM)                  /* 524288 */
#define OFF_TEXT (OFF_KV + 4 * ASTRIDE)          /* 2653696 */
#define OFF_KF   (OFF_TEXT + NG * DM)
#define OFF_VF   (OFF_KF + NG * DM)
/* bf16 transposed weights (stored as shorts inside the float ws) */
#define OFF_W1T  (OFF_VF + NG * DM)              /* 2 * 262144 shorts = 262144 floats */
#define OFF_W2T  (OFF_W1T + 262144)
#define OFF_WQT  (OFF_W2T + 262144)              /* 2 * 16384 shorts = 16384 floats */
#define OFF_WQFT (OFF_WQT + 16384)               /* 16384 shorts = 8192 floats */

typedef __attribute__((ext_vector_type(8))) short bf16x8;
typedef __attribute__((ext_vector_type(4))) float f32x4;
#define MFMA16(a, b, c) __builtin_amdgcn_mfma_f32_16x16x32_bf16(a, b, c, 0, 0, 0)

__device__ __forceinline__ short bfc(float x) {
    union { float f; unsigned u; } v; v.f = x;
    unsigned r = v.u + 0x7fffu + ((v.u >> 16) & 1u);   // RNE
    return (short)(r >> 16);
}

// ---------------- kernel 1: visual = lf @ W_vis ; visn = LN(visual) ----------
__global__ __launch_bounds__(128) void k_visln(const float* __restrict__ lf,
                                               const float* __restrict__ Wvis,
                                               float* __restrict__ visn) {
    __shared__ float xs[16][256];
    __shared__ float vis[16][128];
    __shared__ float part[16][8][2];
    __shared__ float mean_s[16], rstd_s[16];
    const int tid = threadIdx.x;
    const int r0 = blockIdx.x * 16;
    float acc[16];
#pragma unroll
    for (int r = 0; r < 16; ++r) acc[r] = 0.f;
    for (int c = 0; c < 8; ++c) {
        const int k0 = c * 256;
        for (int idx = tid; idx < 16 * 256; idx += 128) {
            int r = idx >> 8, kk = idx & 255;
            xs[r][kk] = lf[(size_t)(r0 + r) * FD + k0 + kk];
        }
        __syncthreads();
        for (int k4 = 0; k4 < 64; ++k4) {
            const float* wp = Wvis + (size_t)(k0 + k4 * 4) * DM + tid;
            float w0 = wp[0 * DM], w1 = wp[1 * DM], w2 = wp[2 * DM], w3 = wp[3 * DM];
#pragma unroll
            for (int r = 0; r < 16; ++r) {
                const float4 x4 = *(const float4*)&xs[r][k4 * 4];
                acc[r] += x4.x * w0 + x4.y * w1 + x4.z * w2 + x4.w * w3;
            }
        }
        __syncthreads();
    }
#pragma unroll
    for (int r = 0; r < 16; ++r) vis[r][tid] = acc[r];
    __syncthreads();
    {
        int r = tid >> 3, p = tid & 7;
        float s = 0.f, s2 = 0.f;
#pragma unroll
        for (int k = 0; k < 16; ++k) { float v = vis[r][p * 16 + k]; s += v; s2 += v * v; }
        part[r][p][0] = s; part[r][p][1] = s2;
    }
    __syncthreads();
    if (tid < 16) {
        float s = 0.f, s2 = 0.f;
#pragma unroll
        for (int p = 0; p < 8; ++p) { s += part[tid][p][0]; s2 += part[tid][p][1]; }
        float m = s * (1.f / 128.f);
        float v = s2 * (1.f / 128.f) - m * m;
        mean_s[tid] = m; rstd_s[tid] = rsqrtf(v + 1e-5f);
    }
    __syncthreads();
#pragma unroll
    for (int r = 0; r < 16; ++r)
        visn[(size_t)(r0 + r) * DM + tid] = (vis[r][tid] - mean_s[r]) * rstd_s[r];
}

// ---------------- kernel 2: K_l / V_l = visn @ Wk_enc[l] / Wv_enc[l] ---------
__global__ __launch_bounds__(128) void k_kvproj(const float* __restrict__ visn,
                                                const float* __restrict__ Wk_enc,
                                                const float* __restrict__ Wv_enc,
                                                float* __restrict__ kv) {
    __shared__ float xs[16][128];
    const int tid = threadIdx.x;
    const int r0 = blockIdx.x * 16;
    const int a = blockIdx.y;
    const float* W = ((a & 1) ? Wv_enc : Wk_enc) + (size_t)(a >> 1) * DM * DM;
    float* out = kv + (size_t)a * ASTRIDE;
    for (int idx = tid; idx < 16 * 128; idx += 128)
        xs[idx >> 7][idx & 127] = visn[(size_t)r0 * DM + idx];
    __syncthreads();
    float acc[16];
#pragma unroll
    for (int r = 0; r < 16; ++r) acc[r] = 0.f;
    for (int k4 = 0; k4 < 32; ++k4) {
        const float* wp = W + (size_t)(k4 * 4) * DM + tid;
        float w0 = wp[0 * DM], w1 = wp[1 * DM], w2 = wp[2 * DM], w3 = wp[3 * DM];
#pragma unroll
        for (int r = 0; r < 16; ++r) {
            const float4 x4 = *(const float4*)&xs[r][k4 * 4];
            acc[r] += x4.x * w0 + x4.y * w1 + x4.z * w2 + x4.w * w3;
        }
    }
#pragma unroll
    for (int r = 0; r < 16; ++r)
        out[(size_t)(PAD + r0 + r) * DM + tid] = acc[r];
}

// -------- kernel 3: text = g @ W_txt ; Kf = text @ Wk_f ; Vf = text @ Wv_f ---
__global__ __launch_bounds__(128) void k_text(const float* __restrict__ g,
                                              const float* __restrict__ Wtxt,
                                              const float* __restrict__ Wkf,
                                              const float* __restrict__ Wvf,
                                              float* __restrict__ text,
                                              float* __restrict__ kf,
                                              float* __restrict__ vf) {
    __shared__ float gs[GFD];
    __shared__ float tr[DM];
    const int r = blockIdx.x;
    const int tid = threadIdx.x;
    for (int i = tid; i < GFD; i += 128) gs[i] = g[(size_t)r * GFD + i];
    __syncthreads();
    float acc = 0.f;
    for (int k = 0; k < GFD; ++k) acc += gs[k] * Wtxt[(size_t)k * DM + tid];
    tr[tid] = acc;
    text[(size_t)r * DM + tid] = acc;
    __syncthreads();
    float a1 = 0.f, a2 = 0.f;
    for (int k = 0; k < DM; ++k) {
        float x = tr[k];
        a1 += x * Wkf[(size_t)k * DM + tid];
        a2 += x * Wvf[(size_t)k * DM + tid];
    }
    kf[(size_t)r * DM + tid] = a1;
    vf[(size_t)r * DM + tid] = a2;
}

// -------- kernel 3b: bf16 transposed weights: W1t[n][k], W2t[n][k], Wqt, Wqft
__global__ __launch_bounds__(256) void k_wcvt(const float* __restrict__ Wq_enc,
                                              const float* __restrict__ W1f,
                                              const float* __restrict__ W2f,
                                              const float* __restrict__ Wqf,
                                              short* __restrict__ W1T,
                                              short* __restrict__ W2T,
                                              short* __restrict__ WQT,
                                              short* __restrict__ WQFT) {
    const int t = blockIdx.x * 256 + threadIdx.x;   // 0..262143
    const int gsel = blockIdx.y;
    if (gsel < 2) {                       // W1T[l][n*128+k] = W1[l][k][n], n<2048,k<128
        int n = t >> 7, k = t & 127;
        W1T[gsel * 262144 + t] = bfc(W1f[(size_t)gsel * 262144 + (size_t)k * FD + n]);
    } else if (gsel < 4) {                // W2T[l][n*2048+k] = W2[l][k][n], n<128,k<2048
        int l = gsel - 2;
        int n = t >> 11, k = t & 2047;
        W2T[l * 262144 + t] = bfc(W2f[(size_t)l * 262144 + (size_t)k * DM + n]);
    } else if (gsel < 6) {                // WQT[l][n*128+k] = Wq_enc[l][k][n]
        int l = gsel - 4;
        if (t < 16384) {
            int n = t >> 7, k = t & 127;
            WQT[l * 16384 + t] = bfc(Wq_enc[(size_t)l * 16384 + k * DM + n]);
        }
    } else {                              // WQFT[n*128+k] = Wqf[k][n]
        if (t < 16384) {
            int n = t >> 7, k = t & 127;
            WQFT[t] = bfc(Wqf[(size_t)k * DM + n]);
        }
    }
}

// ---------------- LN helper for a [16][128] LDS tile -------------------------
__device__ __forceinline__ void ln16x128(const float* __restrict__ src,
                                         float* __restrict__ dst,
                                         float* part2, float* mean_s, float* rstd_s,
                                         int tid) {
    if (tid < 128) {
        int r = tid >> 3, p = tid & 7;
        const float* row = src + r * 128 + p * 16;
        float s = 0.f, s2 = 0.f;
#pragma unroll
        for (int k = 0; k < 16; ++k) { float v = row[k]; s += v; s2 += v * v; }
        part2[tid * 2] = s; part2[tid * 2 + 1] = s2;
    }
    __syncthreads();
    if (tid < 16) {
        float s = 0.f, s2 = 0.f;
#pragma unroll
        for (int p = 0; p < 8; ++p) { s += part2[(tid * 8 + p) * 2]; s2 += part2[(tid * 8 + p) * 2 + 1]; }
        float m = s * (1.f / 128.f);
        float v = s2 * (1.f / 128.f) - m * m;
        mean_s[tid] = m; rstd_s[tid] = rsqrtf(v + 1e-5f);
    }
    __syncthreads();
    for (int o = tid; o < 2048; o += 512) {
        int r = o >> 7;
        dst[o] = (src[o] - mean_s[r]) * rstd_s[r];
    }
    __syncthreads();
}

// ---------------- kernel 4: per-frame encoder + final attention --------------
__global__ __launch_bounds__(512, 4) void k_frames(
    const float* __restrict__ kv,     const float* __restrict__ text,
    const float* __restrict__ kf,     const float* __restrict__ vf,
    const short* __restrict__ W1T,    const short* __restrict__ W2T,
    const short* __restrict__ WQT,    const short* __restrict__ WQFT,
    float* __restrict__ out) {
    __shared__ float t_cur[16][128];
    __shared__ float tqs[16][128];
    __shared__ float qb[16][128];
    __shared__ __align__(16) float sc[128 * SCP];  // scores; FFN Xs/Hs bf16 alias
    __shared__ float part2[256];
    __shared__ float mean_s[16], rstd_s[16];

    short* Xs = (short*)sc;            // [16][136] bf16, +16B row pad (2-way banks)
    short* Hs = ((short*)sc) + 16 * 136;  // [16][520] bf16 (512 + 8 pad)

    const int tid = threadIdx.x;       // 512
    const int T = blockIdx.x;          // frame
    const int j = tid & 127;
    const int r0 = tid >> 7;           // rows r0, r0+4, r0+8, r0+12
    const int w = tid >> 6;            // wave 0..7
    const int lane = tid & 63;
    const int lq = lane & 15;
    const int quad = lane >> 4;

    for (int o = tid; o < 2048; o += 512) (&t_cur[0][0])[o] = text[o];
    __syncthreads();

    for (int l = 0; l < 2; ++l) {
        // tq = LN(t)
        ln16x128(&t_cur[0][0], &tqs[0][0], part2, mean_s, rstd_s, tid);
        // ---- Q = tq @ Wq  (MFMA; wave w owns out cols 16w..16w+15) ----
        {
            for (int o = tid; o < 2048; o += 512)
                Xs[(o >> 7) * 136 + (o & 127)] = bfc((&tqs[0][0])[o]);
            __syncthreads();
            bf16x8 af[4];
#pragma unroll
            for (int ks = 0; ks < 4; ++ks)
                af[ks] = *(bf16x8*)&Xs[lq * 136 + ks * 32 + quad * 8];
            f32x4 acc = {0.f, 0.f, 0.f, 0.f};
            const short* wq = WQT + l * 16384;
#pragma unroll
            for (int ks = 0; ks < 4; ++ks) {
                bf16x8 b = *(const bf16x8*)&wq[(16 * w + lq) * 128 + ks * 32 + quad * 8];
                acc = MFMA16(af[ks], b, acc);
            }
            __syncthreads();            // Xs (alias of sc) free before score writes
#pragma unroll
            for (int r = 0; r < 4; ++r) qb[quad * 4 + r][16 * w + lq] = acc[r];
        }
        __syncthreads();
        // scores: [h][q][k] = Q . K_window / 4
        {
            const float* Kl = kv + (size_t)(2 * l) * ASTRIDE;
#pragma unroll
            for (int i = 0; i < 16; ++i) {
                int s = tid + 512 * i;
                int k = s & 63, gidx = s >> 6;
                int h = gidx >> 4, r = gidx & 15;
                const float* krow = Kl + (size_t)(T + k) * DM + h * DQH;
                const float* qrow = &qb[r][h * DQH];
                float acc = 0.f;
#pragma unroll
                for (int d = 0; d < 16; ++d) acc += qrow[d] * krow[d];
                sc[gidx * SCP + k] = acc * 0.25f;
            }
        }
        __syncthreads();
        // softmax over k per (h,q)
        if (tid < 128) {
            float* row = sc + tid * SCP;
            float mx = row[0];
            for (int k = 1; k < 64; ++k) mx = fmaxf(mx, row[k]);
            float sum = 0.f;
            for (int k = 0; k < 64; ++k) { float e = expf(row[k] - mx); row[k] = e; sum += e; }
            float inv = 1.f / sum;
            for (int k = 0; k < 64; ++k) row[k] *= inv;
        }
        __syncthreads();
        // ctx = attn @ V_window ; + residual tq -> qb
        {
            const float* Vl = kv + (size_t)(2 * l + 1) * ASTRIDE;
            const int h = j >> 4;
            float acc[4] = {0.f, 0.f, 0.f, 0.f};
#pragma unroll 4
            for (int k = 0; k < 64; ++k) {
                float v = Vl[(size_t)(T + k) * DM + j];
#pragma unroll
                for (int rr = 0; rr < 4; ++rr)
                    acc[rr] += sc[(h * 16 + r0 + 4 * rr) * SCP + k] * v;
            }
#pragma unroll
            for (int rr = 0; rr < 4; ++rr)
                qb[r0 + 4 * rr][j] = acc[rr] + tqs[r0 + 4 * rr][j];
        }
        __syncthreads();
        // t = LN(ctx + tq)
        ln16x128(&qb[0][0], &t_cur[0][0], part2, mean_s, rstd_s, tid);
        // x = LN(t) -> tqs
        ln16x128(&t_cur[0][0], &tqs[0][0], part2, mean_s, rstd_s, tid);
        // ---- FFN via MFMA: t = LN(relu(x@W1)@W2 + x) ----
        {
            const short* w1p = W1T + l * 262144;
            const short* w2p = W2T + l * 262144;
            for (int o = tid; o < 2048; o += 512)
                Xs[(o >> 7) * 136 + (o & 127)] = bfc((&tqs[0][0])[o]);
            __syncthreads();
            bf16x8 af[4];
#pragma unroll
            for (int ks = 0; ks < 4; ++ks)
                af[ks] = *(bf16x8*)&Xs[lq * 136 + ks * 32 + quad * 8];
            f32x4 yacc = {0.f, 0.f, 0.f, 0.f};
            for (int c = 0; c < 4; ++c) {
                // GEMM1: H[:, wave cols] = relu(X @ W1[:, c*512 + w*64 .. +63])
#pragma unroll
                for (int nt = 0; nt < 4; ++nt) {
                    f32x4 acc = {0.f, 0.f, 0.f, 0.f};
                    const int n0 = c * 512 + w * 64 + nt * 16;
#pragma unroll
                    for (int ks = 0; ks < 4; ++ks) {
                        bf16x8 b = *(const bf16x8*)&w1p[(n0 + lq) * 128 + ks * 32 + quad * 8];
                        acc = MFMA16(af[ks], b, acc);
                    }
#pragma unroll
                    for (int r = 0; r < 4; ++r)
                        Hs[(quad * 4 + r) * 520 + w * 64 + nt * 16 + lq] = bfc(fmaxf(acc[r], 0.f));
                }
                __syncthreads();
                // GEMM2: Y[:, 16w..16w+15] += H_c @ W2[c rows, :]
#pragma unroll
                for (int kk = 0; kk < 16; ++kk) {
                    bf16x8 ah = *(bf16x8*)&Hs[lq * 520 + kk * 32 + quad * 8];
                    bf16x8 b2 = *(const bf16x8*)&w2p[(16 * w + lq) * 2048 + c * 512 + kk * 32 + quad * 8];
                    yacc = MFMA16(ah, b2, yacc);
                }
                __syncthreads();
            }
#pragma unroll
            for (int r = 0; r < 4; ++r)
                qb[quad * 4 + r][16 * w + lq] = yacc[r] + tqs[quad * 4 + r][16 * w + lq];
        }
        __syncthreads();
        ln16x128(&qb[0][0], &t_cur[0][0], part2, mean_s, rstd_s, tid);
    }

    // ---- final single-head attention: Q = t@Wq_f (MFMA), K/V precomputed ----
    {
        for (int o = tid; o < 2048; o += 512)
            Xs[(o >> 7) * 136 + (o & 127)] = bfc((&t_cur[0][0])[o]);
        __syncthreads();
        bf16x8 af[4];
#pragma unroll
        for (int ks = 0; ks < 4; ++ks)
            af[ks] = *(bf16x8*)&Xs[lq * 136 + ks * 32 + quad * 8];
        f32x4 acc = {0.f, 0.f, 0.f, 0.f};
#pragma unroll
        for (int ks = 0; ks < 4; ++ks) {
            bf16x8 b = *(const bf16x8*)&WQFT[(16 * w + lq) * 128 + ks * 32 + quad * 8];
            acc = MFMA16(af[ks], b, acc);
        }
        __syncthreads();               // Xs free before sc[0..255] writes below
#pragma unroll
        for (int r = 0; r < 4; ++r) tqs[quad * 4 + r][16 * w + lq] = acc[r];
    }
    __syncthreads();
    if (tid < 256) {
        int qr = tid >> 4, kr = tid & 15;
        float acc = 0.f;
#pragma unroll 4
        for (int d = 0; d < DM; ++d) acc += tqs[qr][d] * kf[(size_t)kr * DM + d];
        sc[tid] = acc * 0.08838834764831845f;   // 1/sqrt(128)
    }
    __syncthreads();
    if (tid < 16) {
        float* row = sc + tid * 16;
        float mx = row[0];
        for (int k = 1; k < 16; ++k) mx = fmaxf(mx, row[k]);
        float sum = 0.f;
        for (int k = 0; k < 16; ++k) { float e = expf(row[k] - mx); row[k] = e; sum += e; }
        float inv = 1.f / sum;
        for (int k = 0; k < 16; ++k) row[k] *= inv;
    }
    __syncthreads();
    {
        float acc[4] = {0.f, 0.f, 0.f, 0.f};
#pragma unroll
        for (int k = 0; k < 16; ++k) {
            float v = vf[(size_t)k * DM + j];
#pragma unroll
            for (int rr = 0; rr < 4; ++rr) acc[rr] += sc[(r0 + 4 * rr) * 16 + k] * v;
        }
#pragma unroll
        for (int rr = 0; rr < 4; ++rr)
            qb[r0 + 4 * rr][j] = acc[rr] + t_cur[r0 + 4 * rr][j];
    }
    __syncthreads();
    ln16x128(&qb[0][0], &tqs[0][0], part2, mean_s, rstd_s, tid);
    for (int o = tid; o < 2048; o += 512)
        out[(size_t)T * 2048 + o] = (&tqs[0][0])[o];
}

extern "C" void kernel_launch(void* const* d_in, const int* in_sizes, int n_in,
                              void* d_out, int out_size, void* d_ws, size_t ws_size,
                              hipStream_t stream) {
    const float* g      = (const float*)d_in[0];
    const float* lf     = (const float*)d_in[1];
    const float* Wvis   = (const float*)d_in[2];
    const float* Wtxt   = (const float*)d_in[3];
    const float* Wq_enc = (const float*)d_in[4];
    const float* Wk_enc = (const float*)d_in[5];
    const float* Wv_enc = (const float*)d_in[6];
    const float* W1f    = (const float*)d_in[7];
    const float* W2f    = (const float*)d_in[8];
    const float* Wqf    = (const float*)d_in[9];
    const float* Wkf    = (const float*)d_in[10];
    const float* Wvf    = (const float*)d_in[11];
    float* out = (float*)d_out;
    float* ws  = (float*)d_ws;

    float* visn = ws + OFF_VISN;
    float* kv   = ws + OFF_KV;
    float* text = ws + OFF_TEXT;
    float* kfp  = ws + OFF_KF;
    float* vfp  = ws + OFF_VF;
    short* W1T  = (short*)(ws + OFF_W1T);
    short* W2T  = (short*)(ws + OFF_W2T);
    short* WQT  = (short*)(ws + OFF_WQT);
    short* WQFT = (short*)(ws + OFF_WQFT);

    for (int a = 0; a < 4; ++a)
        hipMemsetAsync(kv + (size_t)a * ASTRIDE, 0, (size_t)PAD * DM * sizeof(float), stream);

    k_wcvt  <<<dim3(1024, 7), dim3(256), 0, stream>>>(Wq_enc, W1f, W2f, Wqf, W1T, W2T, WQT, WQFT);
    k_visln <<<dim3(TFRAMES / 16), dim3(128), 0, stream>>>(lf, Wvis, visn);
    k_kvproj<<<dim3(TFRAMES / 16, 4), dim3(128), 0, stream>>>(visn, Wk_enc, Wv_enc, kv);
    k_text  <<<dim3(NG), dim3(128), 0, stream>>>(g, Wtxt, Wkf, Wvf, text, kfp, vfp);
    k_frames<<<dim3(TFRAMES), dim3(512), 0, stream>>>(kv, text, kfp, vfp, W1T, W2T, WQT, WQFT, out);
}

// Round 3
// 869.807 us; speedup vs baseline: 7.4402x; 2.2930x over previous
//
#include <hip/hip_runtime.h>
#include <math.h>

#define TFRAMES 4096
#define DM 128
#define LQ 64
#define NG 16
#define NH 8
#define DQH 16
#define FD 2048
#define GFD 512
#define PAD 63
#define KVROWS (TFRAMES + PAD)      /* 4159 */
#define ASTRIDE (KVROWS * DM)       /* 532352 floats per K/V array */
#define FPB 8                       /* frames per block */
#define MROWS (FPB * NG)            /* 128 rows of state per block */
#define ST 136                      /* state row stride in shorts (16B-aligned, 68 words -> <=2-way banks) */
#define UROWS (LQ + FPB - 1)        /* 71 K/V union rows */

/* ws layout (floats) */
#define OFF_VISN 0
#define OFF_KV   (TFRAMES * DM)                  /* 524288 */
#define OFF_TEXT (OFF_KV + 4 * ASTRIDE)          /* 2653696 */
#define OFF_KF   (OFF_TEXT + NG * DM)
#define OFF_VF   (OFF_KF + NG * DM)
/* bf16 transposed weights (stored as shorts inside the float ws) */
#define OFF_W1T  (OFF_VF + NG * DM)
#define OFF_W2T  (OFF_W1T + 262144)
#define OFF_WQT  (OFF_W2T + 262144)
#define OFF_WQFT (OFF_WQT + 16384)

typedef __attribute__((ext_vector_type(8))) short bf16x8;
typedef __attribute__((ext_vector_type(4))) float f32x4;
#define MFMA16(a, b, c) __builtin_amdgcn_mfma_f32_16x16x32_bf16(a, b, c, 0, 0, 0)

__device__ __forceinline__ short bfc(float x) {
    union { float f; unsigned u; } v; v.f = x;
    unsigned r = v.u + 0x7fffu + ((v.u >> 16) & 1u);   // RNE
    return (short)(r >> 16);
}
__device__ __forceinline__ float b2f(short s) {
    union { unsigned u; float f; } v;
    v.u = ((unsigned)(unsigned short)s) << 16;
    return v.f;
}

// ---------------- kernel 1: visual = lf @ W_vis ; visn = LN(visual) ----------
__global__ __launch_bounds__(128) void k_visln(const float* __restrict__ lf,
                                               const float* __restrict__ Wvis,
                                               float* __restrict__ visn) {
    __shared__ float xs[16][256];
    __shared__ float vis[16][128];
    __shared__ float part[16][8][2];
    __shared__ float mean_s[16], rstd_s[16];
    const int tid = threadIdx.x;
    const int r0 = blockIdx.x * 16;
    float acc[16];
#pragma unroll
    for (int r = 0; r < 16; ++r) acc[r] = 0.f;
    for (int c = 0; c < 8; ++c) {
        const int k0 = c * 256;
        for (int idx = tid; idx < 16 * 256; idx += 128) {
            int r = idx >> 8, kk = idx & 255;
            xs[r][kk] = lf[(size_t)(r0 + r) * FD + k0 + kk];
        }
        __syncthreads();
        for (int k4 = 0; k4 < 64; ++k4) {
            const float* wp = Wvis + (size_t)(k0 + k4 * 4) * DM + tid;
            float w0 = wp[0 * DM], w1 = wp[1 * DM], w2 = wp[2 * DM], w3 = wp[3 * DM];
#pragma unroll
            for (int r = 0; r < 16; ++r) {
                const float4 x4 = *(const float4*)&xs[r][k4 * 4];
                acc[r] += x4.x * w0 + x4.y * w1 + x4.z * w2 + x4.w * w3;
            }
        }
        __syncthreads();
    }
#pragma unroll
    for (int r = 0; r < 16; ++r) vis[r][tid] = acc[r];
    __syncthreads();
    {
        int r = tid >> 3, p = tid & 7;
        float s = 0.f, s2 = 0.f;
#pragma unroll
        for (int k = 0; k < 16; ++k) { float v = vis[r][p * 16 + k]; s += v; s2 += v * v; }
        part[r][p][0] = s; part[r][p][1] = s2;
    }
    __syncthreads();
    if (tid < 16) {
        float s = 0.f, s2 = 0.f;
#pragma unroll
        for (int p = 0; p < 8; ++p) { s += part[tid][p][0]; s2 += part[tid][p][1]; }
        float m = s * (1.f / 128.f);
        float v = s2 * (1.f / 128.f) - m * m;
        mean_s[tid] = m; rstd_s[tid] = rsqrtf(v + 1e-5f);
    }
    __syncthreads();
#pragma unroll
    for (int r = 0; r < 16; ++r)
        visn[(size_t)(r0 + r) * DM + tid] = (vis[r][tid] - mean_s[r]) * rstd_s[r];
}

// ---------------- kernel 2: K_l / V_l = visn @ Wk_enc[l] / Wv_enc[l] ---------
__global__ __launch_bounds__(128) void k_kvproj(const float* __restrict__ visn,
                                                const float* __restrict__ Wk_enc,
                                                const float* __restrict__ Wv_enc,
                                                float* __restrict__ kv) {
    __shared__ float xs[16][128];
    const int tid = threadIdx.x;
    const int r0 = blockIdx.x * 16;
    const int a = blockIdx.y;
    const float* W = ((a & 1) ? Wv_enc : Wk_enc) + (size_t)(a >> 1) * DM * DM;
    float* out = kv + (size_t)a * ASTRIDE;
    for (int idx = tid; idx < 16 * 128; idx += 128)
        xs[idx >> 7][idx & 127] = visn[(size_t)r0 * DM + idx];
    __syncthreads();
    float acc[16];
#pragma unroll
    for (int r = 0; r < 16; ++r) acc[r] = 0.f;
    for (int k4 = 0; k4 < 32; ++k4) {
        const float* wp = W + (size_t)(k4 * 4) * DM + tid;
        float w0 = wp[0 * DM], w1 = wp[1 * DM], w2 = wp[2 * DM], w3 = wp[3 * DM];
#pragma unroll
        for (int r = 0; r < 16; ++r) {
            const float4 x4 = *(const float4*)&xs[r][k4 * 4];
            acc[r] += x4.x * w0 + x4.y * w1 + x4.z * w2 + x4.w * w3;
        }
    }
#pragma unroll
    for (int r = 0; r < 16; ++r)
        out[(size_t)(PAD + r0 + r) * DM + tid] = acc[r];
}

// -------- kernel 3: text = g @ W_txt ; Kf = text @ Wk_f ; Vf = text @ Wv_f ---
__global__ __launch_bounds__(128) void k_text(const float* __restrict__ g,
                                              const float* __restrict__ Wtxt,
                                              const float* __restrict__ Wkf,
                                              const float* __restrict__ Wvf,
                                              float* __restrict__ text,
                                              float* __restrict__ kf,
                                              float* __restrict__ vf) {
    __shared__ float gs[GFD];
    __shared__ float tr[DM];
    const int r = blockIdx.x;
    const int tid = threadIdx.x;
    for (int i = tid; i < GFD; i += 128) gs[i] = g[(size_t)r * GFD + i];
    __syncthreads();
    float acc = 0.f;
    for (int k = 0; k < GFD; ++k) acc += gs[k] * Wtxt[(size_t)k * DM + tid];
    tr[tid] = acc;
    text[(size_t)r * DM + tid] = acc;
    __syncthreads();
    float a1 = 0.f, a2 = 0.f;
    for (int k = 0; k < DM; ++k) {
        float x = tr[k];
        a1 += x * Wkf[(size_t)k * DM + tid];
        a2 += x * Wvf[(size_t)k * DM + tid];
    }
    kf[(size_t)r * DM + tid] = a1;
    vf[(size_t)r * DM + tid] = a2;
}

// -------- kernel 3b: bf16 transposed weights: W1t[n][k], W2t[n][k], Wqt, Wqft
__global__ __launch_bounds__(256) void k_wcvt(const float* __restrict__ Wq_enc,
                                              const float* __restrict__ W1f,
                                              const float* __restrict__ W2f,
                                              const float* __restrict__ Wqf,
                                              short* __restrict__ W1T,
                                              short* __restrict__ W2T,
                                              short* __restrict__ WQT,
                                              short* __restrict__ WQFT) {
    const int t = blockIdx.x * 256 + threadIdx.x;
    const int gsel = blockIdx.y;
    if (gsel < 2) {
        int n = t >> 7, k = t & 127;
        W1T[gsel * 262144 + t] = bfc(W1f[(size_t)gsel * 262144 + (size_t)k * FD + n]);
    } else if (gsel < 4) {
        int l = gsel - 2;
        int n = t >> 11, k = t & 2047;
        W2T[l * 262144 + t] = bfc(W2f[(size_t)l * 262144 + (size_t)k * DM + n]);
    } else if (gsel < 6) {
        int l = gsel - 4;
        if (t < 16384) {
            int n = t >> 7, k = t & 127;
            WQT[l * 16384 + t] = bfc(Wq_enc[(size_t)l * 16384 + k * DM + n]);
        }
    } else {
        if (t < 16384) {
            int n = t >> 7, k = t & 127;
            WQFT[t] = bfc(Wqf[(size_t)k * DM + n]);
        }
    }
}

// ------------- LN over a [128][ST] bf16 LDS tile, bf16 out -------------------
// dbl!=0: computes LN(LN(x)) exactly via adjusted scale (mean(LN)=0, var=v/(v+eps))
__device__ __forceinline__ void ln_pass(const short* src, short* dst, int tid, int dbl,
                                        float* pa, float* pb, float* ms, float* rs) {
    {
        int row = tid >> 2, p = tid & 3;
        const bf16x8* bp = (const bf16x8*)(src + row * ST + p * 32);
        float s = 0.f, s2 = 0.f;
#pragma unroll
        for (int q8 = 0; q8 < 4; ++q8) {
            bf16x8 x = bp[q8];
#pragma unroll
            for (int e = 0; e < 8; ++e) { float v = b2f(x[e]); s += v; s2 += v * v; }
        }
        pa[tid] = s; pb[tid] = s2;
    }
    __syncthreads();
    if (tid < 128) {
        float s = 0.f, s2 = 0.f;
#pragma unroll
        for (int p = 0; p < 4; ++p) { s += pa[tid * 4 + p]; s2 += pb[tid * 4 + p]; }
        float m = s * (1.f / 128.f);
        float v = s2 * (1.f / 128.f) - m * m;
        float r = rsqrtf(v + 1e-5f);
        if (dbl) r *= rsqrtf(v / (v + 1e-5f) + 1e-5f);
        ms[tid] = m; rs[tid] = r;
    }
    __syncthreads();
    {
        int row = tid >> 2, p = tid & 3;
        float m = ms[row], r = rs[row];
        const bf16x8* sp = (const bf16x8*)(src + row * ST + p * 32);
        bf16x8* dp = (bf16x8*)(dst + row * ST + p * 32);
#pragma unroll
        for (int q8 = 0; q8 < 4; ++q8) {
            bf16x8 x = sp[q8]; bf16x8 o;
#pragma unroll
            for (int e = 0; e < 8; ++e) o[e] = bfc((b2f(x[e]) - m) * r);
            dp[q8] = o;
        }
    }
    __syncthreads();
}

// ---------------- kernel 4: 8 frames per block, fused encoder ----------------
__global__ __launch_bounds__(512, 2) void k_frames(
    const float* __restrict__ kv,     const float* __restrict__ text,
    const float* __restrict__ kf,     const float* __restrict__ vf,
    const short* __restrict__ W1T,    const short* __restrict__ W2T,
    const short* __restrict__ WQT,    const short* __restrict__ WQFT,
    float* __restrict__ out) {
    __shared__ __align__(16) short sUa[MROWS * ST];    // state buffer A
    __shared__ __align__(16) short sUb[MROWS * ST];    // state buffer B
    __shared__ __align__(16) short sK[UROWS * ST];     // K union (bf16)
    __shared__ __align__(16) short sV[UROWS * ST];     // V union (bf16)
    __shared__ __align__(16) short sHS[MROWS * ST];    // Q / H-chunk / z3 scratch
    __shared__ float sPa[512], sPb[512];
    __shared__ float sMean[128], sRstd[128];

    const int tid = threadIdx.x;        // 512 = 8 waves
    const int w = tid >> 6;             // wave id 0..7
    const int lane = tid & 63;
    const int lq = lane & 15;
    const int quad = lane >> 4;
    const int T0 = blockIdx.x * FPB;    // first frame of this block

    short* st0 = sUa;                   // holds t at layer entry
    short* st1 = sUb;

    // init: t rows m=f*16+q <- text[q][:]
    for (int o = tid; o < MROWS * 128; o += 512) {
        int m = o >> 7;
        st0[m * ST + (o & 127)] = bfc(text[(m & 15) * 128 + (o & 127)]);
    }
    __syncthreads();

    for (int l = 0; l < 2; ++l) {
        // ---- stage K/V union for this layer (padded rows T0 .. T0+70) ----
        for (int o = tid; o < UROWS * 128; o += 512) {
            int u = o >> 7, c = o & 127;
            sK[u * ST + c] = bfc(kv[(size_t)(2 * l) * ASTRIDE + (size_t)(T0 + u) * DM + c]);
            sV[u * ST + c] = bfc(kv[(size_t)(2 * l + 1) * ASTRIDE + (size_t)(T0 + u) * DM + c]);
        }
        // (consumed only after several __syncthreads below)

        // ---- tq = LN(t): st0 -> st1 ----
        ln_pass(st0, st1, tid, 0, sPa, sPb, sMean, sRstd);

        // ---- Q = tq @ Wq[l] -> sHS (bf16) ; wave w owns out cols 16w.. ----
        {
            const short* wq = WQT + l * 16384;
            bf16x8 B[4];
#pragma unroll
            for (int ks = 0; ks < 4; ++ks)
                B[ks] = *(const bf16x8*)&wq[(w * 16 + lq) * 128 + ks * 32 + quad * 8];
#pragma unroll
            for (int mt = 0; mt < 8; ++mt) {
                f32x4 acc = {0.f, 0.f, 0.f, 0.f};
#pragma unroll
                for (int ks = 0; ks < 4; ++ks) {
                    bf16x8 A = *(const bf16x8*)&st1[(mt * 16 + lq) * ST + ks * 32 + quad * 8];
                    acc = MFMA16(A, B[ks], acc);
                }
#pragma unroll
                for (int r = 0; r < 4; ++r)
                    sHS[(mt * 16 + quad * 4 + r) * ST + w * 16 + lq] = bfc(acc[r]);
            }
        }
        __syncthreads();

        // ---- attention: wave w handles frame f=w entirely (no block syncs) --
        // lane roles: q = lane>>2 (query row), kq = lane&3 (16-key quarter)
        {
            const int q = lane >> 2, kq = lane & 3;
            const short* Qrow = &sHS[(w * 16 + q) * ST];
            for (int h = 0; h < NH; ++h) {
                float qv[16];
                {
                    const bf16x8* qp = (const bf16x8*)(Qrow + h * 16);
                    bf16x8 q0 = qp[0], q1 = qp[1];
#pragma unroll
                    for (int e = 0; e < 8; ++e) { qv[e] = b2f(q0[e]); qv[8 + e] = b2f(q1[e]); }
                }
                float sv[16];
#pragma unroll
                for (int kk = 0; kk < 16; ++kk) {
                    const bf16x8* kp = (const bf16x8*)&sK[(w + kq * 16 + kk) * ST + h * 16];
                    bf16x8 k0 = kp[0], k1 = kp[1];
                    float a = 0.f;
#pragma unroll
                    for (int e = 0; e < 8; ++e)
                        a += qv[e] * b2f(k0[e]) + qv[8 + e] * b2f(k1[e]);
                    sv[kk] = a * 0.25f;
                }
                // softmax across the 64 keys (16 local + butterfly over 4 lanes)
                float mx = sv[0];
#pragma unroll
                for (int kk = 1; kk < 16; ++kk) mx = fmaxf(mx, sv[kk]);
                mx = fmaxf(mx, __shfl_xor(mx, 1));
                mx = fmaxf(mx, __shfl_xor(mx, 2));
                float sum = 0.f;
#pragma unroll
                for (int kk = 0; kk < 16; ++kk) { sv[kk] = expf(sv[kk] - mx); sum += sv[kk]; }
                sum += __shfl_xor(sum, 1);
                sum += __shfl_xor(sum, 2);
                float inv = 1.f / sum;
                // ctx partials over this lane's 16 keys, all 16 dims of head h
                float pd[16];
#pragma unroll
                for (int d = 0; d < 16; ++d) pd[d] = 0.f;
#pragma unroll
                for (int kk = 0; kk < 16; ++kk) {
                    const bf16x8* vp = (const bf16x8*)&sV[(w + kq * 16 + kk) * ST + h * 16];
                    bf16x8 v0 = vp[0], v1 = vp[1];
                    float a = sv[kk];
#pragma unroll
                    for (int e = 0; e < 8; ++e) { pd[e] += a * b2f(v0[e]); pd[8 + e] += a * b2f(v1[e]); }
                }
#pragma unroll
                for (int d = 0; d < 16; ++d) {
                    pd[d] += __shfl_xor(pd[d], 1);
                    pd[d] += __shfl_xor(pd[d], 2);
                    pd[d] *= inv;
                }
                // z = ctx + tq : this lane writes its d-quarter (no duplication)
#pragma unroll
                for (int dd = 0; dd < 4; ++dd) {
                    int col = h * 16 + kq * 4 + dd;
                    int row = w * 16 + q;
                    st0[row * ST + col] = bfc(pd[kq * 4 + dd] + b2f(st1[row * ST + col]));
                }
            }
        }
        __syncthreads();

        // ---- x = LN(LN(z)) fused: st0 -> st1 ----
        ln_pass(st0, st1, tid, 1, sPa, sPb, sMean, sRstd);

        // ---- FFN: z2 = relu(x@W1)@W2 + x -> st0 ----
        {
            const short* w1p = W1T + l * 262144;
            const short* w2p = W2T + l * 262144;
            // X A-fragments register-resident for the whole FFN
            bf16x8 XA[8][4];
#pragma unroll
            for (int mt = 0; mt < 8; ++mt)
#pragma unroll
                for (int ks = 0; ks < 4; ++ks)
                    XA[mt][ks] = *(const bf16x8*)&st1[(mt * 16 + lq) * ST + ks * 32 + quad * 8];
            const int nw = w & 3, mw = w >> 2;   // GEMM2 2-D wave split
            f32x4 yacc[4][2];
#pragma unroll
            for (int a = 0; a < 4; ++a)
#pragma unroll
                for (int b = 0; b < 2; ++b) yacc[a][b] = (f32x4){0.f, 0.f, 0.f, 0.f};
            for (int c = 0; c < 16; ++c) {
                // GEMM1: H-chunk cols [c*128, c*128+128); wave w -> ntile w
                {
                    bf16x8 B[4];
#pragma unroll
                    for (int ks = 0; ks < 4; ++ks)
                        B[ks] = *(const bf16x8*)&w1p[(c * 128 + w * 16 + lq) * 128 + ks * 32 + quad * 8];
#pragma unroll
                    for (int mt = 0; mt < 8; ++mt) {
                        f32x4 acc = {0.f, 0.f, 0.f, 0.f};
#pragma unroll
                        for (int ks = 0; ks < 4; ++ks) acc = MFMA16(XA[mt][ks], B[ks], acc);
#pragma unroll
                        for (int r = 0; r < 4; ++r)
                            sHS[(mt * 16 + quad * 4 + r) * ST + w * 16 + lq] = bfc(fmaxf(acc[r], 0.f));
                    }
                }
                __syncthreads();
                // GEMM2: Y[mw rows, nw cols] += H_chunk @ W2[c*128.., :]
#pragma unroll
                for (int ks = 0; ks < 4; ++ks) {
                    bf16x8 B0 = *(const bf16x8*)&w2p[(nw * 32 + lq) * 2048 + c * 128 + ks * 32 + quad * 8];
                    bf16x8 B1 = *(const bf16x8*)&w2p[(nw * 32 + 16 + lq) * 2048 + c * 128 + ks * 32 + quad * 8];
#pragma unroll
                    for (int mt = 0; mt < 4; ++mt) {
                        bf16x8 A = *(const bf16x8*)&sHS[((mw * 4 + mt) * 16 + lq) * ST + ks * 32 + quad * 8];
                        yacc[mt][0] = MFMA16(A, B0, yacc[mt][0]);
                        yacc[mt][1] = MFMA16(A, B1, yacc[mt][1]);
                    }
                }
                __syncthreads();
            }
            // z2 = Y + x -> st0
#pragma unroll
            for (int mt = 0; mt < 4; ++mt)
#pragma unroll
                for (int nt = 0; nt < 2; ++nt)
#pragma unroll
                    for (int r = 0; r < 4; ++r) {
                        int row = (mw * 4 + mt) * 16 + quad * 4 + r;
                        int col = nw * 32 + nt * 16 + lq;
                        st0[row * ST + col] = bfc(yacc[mt][nt][r] + b2f(st1[row * ST + col]));
                    }
        }
        __syncthreads();

        // ---- t = LN(z2): st0 -> st1 ----
        ln_pass(st0, st1, tid, 0, sPa, sPb, sMean, sRstd);
        { short* tmp = st0; st0 = st1; st1 = tmp; }   // t back in st0
    }

    // ================= final single-head attention (d_q = 128) ==============
    // Qf = t @ Wq_f (t NOT normalized; residual = t)
    {
        bf16x8 B[4];
#pragma unroll
        for (int ks = 0; ks < 4; ++ks)
            B[ks] = *(const bf16x8*)&WQFT[(w * 16 + lq) * 128 + ks * 32 + quad * 8];
#pragma unroll
        for (int mt = 0; mt < 8; ++mt) {
            f32x4 acc = {0.f, 0.f, 0.f, 0.f};
#pragma unroll
            for (int ks = 0; ks < 4; ++ks) {
                bf16x8 A = *(const bf16x8*)&st0[(mt * 16 + lq) * ST + ks * 32 + quad * 8];
                acc = MFMA16(A, B[ks], acc);
            }
#pragma unroll
            for (int r = 0; r < 4; ++r)
                sHS[(mt * 16 + quad * 4 + r) * ST + w * 16 + lq] = bfc(acc[r]);
        }
    }
    // stage kf/vf (bf16) + score buffer into dead st1
    short* kfL = st1;
    short* vfL = st1 + 16 * ST;
    float* scF = (float*)(st1 + 2 * 16 * ST);    // [128][17] fp32
    for (int o = tid; o < 2048; o += 512) {
        int kr = o >> 7, c = o & 127;
        kfL[kr * ST + c] = bfc(kf[o]);
        vfL[kr * ST + c] = bfc(vf[o]);
    }
    __syncthreads();
    // scoresF[m][k] = Qf[m] . kf[k] / sqrt(128)
    {
        int m = tid >> 2, kq = tid & 3;
        float a4[4] = {0.f, 0.f, 0.f, 0.f};
        for (int d8 = 0; d8 < 16; ++d8) {
            bf16x8 qc = *(const bf16x8*)&sHS[m * ST + d8 * 8];
            float qf[8];
#pragma unroll
            for (int e = 0; e < 8; ++e) qf[e] = b2f(qc[e]);
#pragma unroll
            for (int k = 0; k < 4; ++k) {
                bf16x8 kc = *(const bf16x8*)&kfL[(kq * 4 + k) * ST + d8 * 8];
#pragma unroll
                for (int e = 0; e < 8; ++e) a4[k] += qf[e] * b2f(kc[e]);
            }
        }
#pragma unroll
        for (int k = 0; k < 4; ++k)
            scF[m * 17 + kq * 4 + k] = a4[k] * 0.08838834764831845f;
    }
    __syncthreads();
    if (tid < 128) {
        float* row = scF + tid * 17;
        float mx = row[0];
#pragma unroll
        for (int k = 1; k < 16; ++k) mx = fmaxf(mx, row[k]);
        float sum = 0.f;
#pragma unroll
        for (int k = 0; k < 16; ++k) { float e = expf(row[k] - mx); row[k] = e; sum += e; }
        float inv = 1.f / sum;
#pragma unroll
        for (int k = 0; k < 16; ++k) row[k] *= inv;
    }
    __syncthreads();
    // z3 = attn @ vf + t -> sHS (bf16)
    {
        int jj = tid & 127, rr0 = tid >> 7;
        float vv[16];
#pragma unroll
        for (int k = 0; k < 16; ++k) vv[k] = b2f(vfL[k * ST + jj]);
        for (int rr = 0; rr < 32; ++rr) {
            int row = rr0 + 4 * rr;
            float acc = 0.f;
#pragma unroll
            for (int k = 0; k < 16; ++k) acc += scF[row * 17 + k] * vv[k];
            sHS[row * ST + jj] = bfc(acc + b2f(st0[row * ST + jj]));
        }
    }
    __syncthreads();
    // out = LN(z3), fp32, contiguous 16384 floats per block
    {
        int row = tid >> 2, p = tid & 3;
        const bf16x8* bp = (const bf16x8*)(sHS + row * ST + p * 32);
        float s = 0.f, s2 = 0.f;
#pragma unroll
        for (int q8 = 0; q8 < 4; ++q8) {
            bf16x8 x = bp[q8];
#pragma unroll
            for (int e = 0; e < 8; ++e) { float v = b2f(x[e]); s += v; s2 += v * v; }
        }
        sPa[tid] = s; sPb[tid] = s2;
    }
    __syncthreads();
    if (tid < 128) {
        float s = 0.f, s2 = 0.f;
#pragma unroll
        for (int p = 0; p < 4; ++p) { s += sPa[tid * 4 + p]; s2 += sPb[tid * 4 + p]; }
        float m = s * (1.f / 128.f);
        float v = s2 * (1.f / 128.f) - m * m;
        sMean[tid] = m; sRstd[tid] = rsqrtf(v + 1e-5f);
    }
    __syncthreads();
    for (int o = tid; o < MROWS * 128; o += 512) {
        int r = o >> 7;
        out[(size_t)T0 * 2048 + o] = (b2f(sHS[r * ST + (o & 127)]) - sMean[r]) * sRstd[r];
    }
}

extern "C" void kernel_launch(void* const* d_in, const int* in_sizes, int n_in,
                              void* d_out, int out_size, void* d_ws, size_t ws_size,
                              hipStream_t stream) {
    const float* g      = (const float*)d_in[0];
    const float* lf     = (const float*)d_in[1];
    const float* Wvis   = (const float*)d_in[2];
    const float* Wtxt   = (const float*)d_in[3];
    const float* Wq_enc = (const float*)d_in[4];
    const float* Wk_enc = (const float*)d_in[5];
    const float* Wv_enc = (const float*)d_in[6];
    const float* W1f    = (const float*)d_in[7];
    const float* W2f    = (const float*)d_in[8];
    const float* Wqf    = (const float*)d_in[9];
    const float* Wkf    = (const float*)d_in[10];
    const float* Wvf    = (const float*)d_in[11];
    float* out = (float*)d_out;
    float* ws  = (float*)d_ws;

    float* visn = ws + OFF_VISN;
    float* kv   = ws + OFF_KV;
    float* text = ws + OFF_TEXT;
    float* kfp  = ws + OFF_KF;
    float* vfp  = ws + OFF_VF;
    short* W1T  = (short*)(ws + OFF_W1T);
    short* W2T  = (short*)(ws + OFF_W2T);
    short* WQT  = (short*)(ws + OFF_WQT);
    short* WQFT = (short*)(ws + OFF_WQFT);

    for (int a = 0; a < 4; ++a)
        hipMemsetAsync(kv + (size_t)a * ASTRIDE, 0, (size_t)PAD * DM * sizeof(float), stream);

    k_wcvt  <<<dim3(1024, 7), dim3(256), 0, stream>>>(Wq_enc, W1f, W2f, Wqf, W1T, W2T, WQT, WQFT);
    k_visln <<<dim3(TFRAMES / 16), dim3(128), 0, stream>>>(lf, Wvis, visn);
    k_kvproj<<<dim3(TFRAMES / 16, 4), dim3(128), 0, stream>>>(visn, Wk_enc, Wv_enc, kv);
    k_text  <<<dim3(NG), dim3(128), 0, stream>>>(g, Wtxt, Wkf, Wvf, text, kfp, vfp);
    k_frames<<<dim3(TFRAMES / FPB), dim3(512), 0, stream>>>(kv, text, kfp, vfp, W1T, W2T, WQT, WQFT, out);
}

// Round 6
// 724.838 us; speedup vs baseline: 8.9283x; 1.2000x over previous
//
#include <hip/hip_runtime.h>
#include <math.h>

#define TFRAMES 4096
#define DM 128
#define LQ 64
#define NG 16
#define NH 8
#define DQH 16
#define FD 2048
#define GFD 512
#define PAD 63
#define KVROWS (TFRAMES + PAD)      /* 4159 */
#define ASTRIDE (KVROWS * DM)       /* 532352 SHORTS per bf16 K/V array */
#define FPB 4                       /* frames per block */
#define MROWS (FPB * NG)            /* 64 state rows per block */
#define STS 136                     /* state row stride (shorts, mult of 8) */
#define VTS 72                      /* V^T row stride (shorts) */
#define PBS 72                      /* P buffer row stride (shorts) */
#define UROWS (LQ + FPB - 1)        /* 67 K/V union rows */

/* ws layout (floats) */
#define OFF_VISN 0
#define OFF_KV   (TFRAMES * DM)                    /* 524288 */
#define OFF_TEXT (OFF_KV + 2 * ASTRIDE)            /* kv is bf16: 4*ASTRIDE shorts = 2*ASTRIDE floats */
#define OFF_KF   (OFF_TEXT + NG * DM)
#define OFF_VF   (OFF_KF + NG * DM)
#define OFF_W1T  (OFF_VF + NG * DM)
#define OFF_W2T  (OFF_W1T + 262144)
#define OFF_WQT  (OFF_W2T + 262144)
#define OFF_WQFT (OFF_WQT + 16384)

typedef __attribute__((ext_vector_type(8))) short bf16x8;
typedef __attribute__((ext_vector_type(4))) float f32x4;
#define MFMA16(a, b, c) __builtin_amdgcn_mfma_f32_16x16x32_bf16(a, b, c, 0, 0, 0)

__device__ __forceinline__ short bfc(float x) {
    union { float f; unsigned u; } v; v.f = x;
    unsigned r = v.u + 0x7fffu + ((v.u >> 16) & 1u);   // RNE
    return (short)(r >> 16);
}
__device__ __forceinline__ float b2f(short s) {
    union { unsigned u; float f; } v;
    v.u = ((unsigned)(unsigned short)s) << 16;
    return v.f;
}
// Extract 8 shorts starting at short-offset f (0..3) from the 12-short window
// {a.x..a.w, b.x, b.y}. v_alignbit_b32 shift is 5-bit (wraps at 32!), so split
// f into a word offset (wo = f>>1, uniform select) + residual 0/16-bit shift.
__device__ __forceinline__ bf16x8 shiftf(int4 a, int4 b, int f) {
    const int wo = f >> 1;
    const int sh = (f & 1) * 16;
    int w0 = wo ? a.y : a.x;
    int w1 = wo ? a.z : a.y;
    int w2 = wo ? a.w : a.z;
    int w3 = wo ? b.x : a.w;
    int w4 = wo ? b.y : b.x;
    int o0 = __builtin_amdgcn_alignbit(w1, w0, sh);
    int o1 = __builtin_amdgcn_alignbit(w2, w1, sh);
    int o2 = __builtin_amdgcn_alignbit(w3, w2, sh);
    int o3 = __builtin_amdgcn_alignbit(w4, w3, sh);
    int4 o = {o0, o1, o2, o3};
    return *(bf16x8*)&o;
}

// ---------------- kernel 1: visual = lf @ W_vis ; visn = LN(visual) ----------
__global__ __launch_bounds__(128) void k_visln(const float* __restrict__ lf,
                                               const float* __restrict__ Wvis,
                                               float* __restrict__ visn) {
    __shared__ float xs[16][256];
    __shared__ float vis[16][128];
    __shared__ float part[16][8][2];
    __shared__ float mean_s[16], rstd_s[16];
    const int tid = threadIdx.x;
    const int r0 = blockIdx.x * 16;
    float acc[16];
#pragma unroll
    for (int r = 0; r < 16; ++r) acc[r] = 0.f;
    for (int c = 0; c < 8; ++c) {
        const int k0 = c * 256;
        for (int idx = tid; idx < 16 * 256; idx += 128) {
            int r = idx >> 8, kk = idx & 255;
            xs[r][kk] = lf[(size_t)(r0 + r) * FD + k0 + kk];
        }
        __syncthreads();
        for (int k4 = 0; k4 < 64; ++k4) {
            const float* wp = Wvis + (size_t)(k0 + k4 * 4) * DM + tid;
            float w0 = wp[0 * DM], w1 = wp[1 * DM], w2 = wp[2 * DM], w3 = wp[3 * DM];
#pragma unroll
            for (int r = 0; r < 16; ++r) {
                const float4 x4 = *(const float4*)&xs[r][k4 * 4];
                acc[r] += x4.x * w0 + x4.y * w1 + x4.z * w2 + x4.w * w3;
            }
        }
        __syncthreads();
    }
#pragma unroll
    for (int r = 0; r < 16; ++r) vis[r][tid] = acc[r];
    __syncthreads();
    {
        int r = tid >> 3, p = tid & 7;
        float s = 0.f, s2 = 0.f;
#pragma unroll
        for (int k = 0; k < 16; ++k) { float v = vis[r][p * 16 + k]; s += v; s2 += v * v; }
        part[r][p][0] = s; part[r][p][1] = s2;
    }
    __syncthreads();
    if (tid < 16) {
        float s = 0.f, s2 = 0.f;
#pragma unroll
        for (int p = 0; p < 8; ++p) { s += part[tid][p][0]; s2 += part[tid][p][1]; }
        float m = s * (1.f / 128.f);
        float v = s2 * (1.f / 128.f) - m * m;
        mean_s[tid] = m; rstd_s[tid] = rsqrtf(v + 1e-5f);
    }
    __syncthreads();
#pragma unroll
    for (int r = 0; r < 16; ++r)
        visn[(size_t)(r0 + r) * DM + tid] = (vis[r][tid] - mean_s[r]) * rstd_s[r];
}

// ------- kernel 2: K_l / V_l = visn @ Wk/Wv  -> bf16, 63 zero rows at head ---
__global__ __launch_bounds__(128) void k_kvproj(const float* __restrict__ visn,
                                                const float* __restrict__ Wk_enc,
                                                const float* __restrict__ Wv_enc,
                                                short* __restrict__ kvB) {
    __shared__ float xs[16][128];
    const int tid = threadIdx.x;
    const int r0 = blockIdx.x * 16;
    const int a = blockIdx.y;
    const float* W = ((a & 1) ? Wv_enc : Wk_enc) + (size_t)(a >> 1) * DM * DM;
    short* out = kvB + (size_t)a * ASTRIDE;
    for (int idx = tid; idx < 16 * 128; idx += 128)
        xs[idx >> 7][idx & 127] = visn[(size_t)r0 * DM + idx];
    __syncthreads();
    float acc[16];
#pragma unroll
    for (int r = 0; r < 16; ++r) acc[r] = 0.f;
    for (int k4 = 0; k4 < 32; ++k4) {
        const float* wp = W + (size_t)(k4 * 4) * DM + tid;
        float w0 = wp[0 * DM], w1 = wp[1 * DM], w2 = wp[2 * DM], w3 = wp[3 * DM];
#pragma unroll
        for (int r = 0; r < 16; ++r) {
            const float4 x4 = *(const float4*)&xs[r][k4 * 4];
            acc[r] += x4.x * w0 + x4.y * w1 + x4.z * w2 + x4.w * w3;
        }
    }
#pragma unroll
    for (int r = 0; r < 16; ++r)
        out[(size_t)(PAD + r0 + r) * DM + tid] = bfc(acc[r]);
}

// -------- kernel 3: text = g @ W_txt ; Kf = text @ Wk_f ; Vf = text @ Wv_f ---
__global__ __launch_bounds__(128) void k_text(const float* __restrict__ g,
                                              const float* __restrict__ Wtxt,
                                              const float* __restrict__ Wkf,
                                              const float* __restrict__ Wvf,
                                              float* __restrict__ text,
                                              float* __restrict__ kf,
                                              float* __restrict__ vf) {
    __shared__ float gs[GFD];
    __shared__ float tr[DM];
    const int r = blockIdx.x;
    const int tid = threadIdx.x;
    for (int i = tid; i < GFD; i += 128) gs[i] = g[(size_t)r * GFD + i];
    __syncthreads();
    float acc = 0.f;
    for (int k = 0; k < GFD; ++k) acc += gs[k] * Wtxt[(size_t)k * DM + tid];
    tr[tid] = acc;
    text[(size_t)r * DM + tid] = acc;
    __syncthreads();
    float a1 = 0.f, a2 = 0.f;
    for (int k = 0; k < DM; ++k) {
        float x = tr[k];
        a1 += x * Wkf[(size_t)k * DM + tid];
        a2 += x * Wvf[(size_t)k * DM + tid];
    }
    kf[(size_t)r * DM + tid] = a1;
    vf[(size_t)r * DM + tid] = a2;
}

// -------- kernel 3b: bf16 transposed weights: W1t[n][k], W2t[n][k], Wqt, Wqft
__global__ __launch_bounds__(256) void k_wcvt(const float* __restrict__ Wq_enc,
                                              const float* __restrict__ W1f,
                                              const float* __restrict__ W2f,
                                              const float* __restrict__ Wqf,
                                              short* __restrict__ W1T,
                                              short* __restrict__ W2T,
                                              short* __restrict__ WQT,
                                              short* __restrict__ WQFT) {
    const int t = blockIdx.x * 256 + threadIdx.x;
    const int gsel = blockIdx.y;
    if (gsel < 2) {
        int n = t >> 7, k = t & 127;
        W1T[gsel * 262144 + t] = bfc(W1f[(size_t)gsel * 262144 + (size_t)k * FD + n]);
    } else if (gsel < 4) {
        int l = gsel - 2;
        int n = t >> 11, k = t & 2047;
        W2T[l * 262144 + t] = bfc(W2f[(size_t)l * 262144 + (size_t)k * DM + n]);
    } else if (gsel < 6) {
        int l = gsel - 4;
        if (t < 16384) {
            int n = t >> 7, k = t & 127;
            WQT[l * 16384 + t] = bfc(Wq_enc[(size_t)l * 16384 + k * DM + n]);
        }
    } else {
        if (t < 16384) {
            int n = t >> 7, k = t & 127;
            WQFT[t] = bfc(Wqf[(size_t)k * DM + n]);
        }
    }
}

// ---------------- LN helpers for [64][STS] bf16 LDS tile ---------------------
__device__ __forceinline__ void ln_stats64(const short* buf, int tid, int dbl,
                                           float* pa, float* pb, float* ms, float* rs) {
    {
        int row = tid >> 3, p = tid & 7;
        const bf16x8* bp = (const bf16x8*)(buf + row * STS + p * 16);
        float s = 0.f, s2 = 0.f;
#pragma unroll
        for (int q8 = 0; q8 < 2; ++q8) {
            bf16x8 x = bp[q8];
#pragma unroll
            for (int e = 0; e < 8; ++e) { float v = b2f(x[e]); s += v; s2 += v * v; }
        }
        pa[tid] = s; pb[tid] = s2;
    }
    __syncthreads();
    if (tid < 64) {
        float ss = 0.f, ss2 = 0.f;
#pragma unroll
        for (int p2 = 0; p2 < 8; ++p2) { ss += pa[tid * 8 + p2]; ss2 += pb[tid * 8 + p2]; }
        float m = ss * (1.f / 128.f);
        float v = ss2 * (1.f / 128.f) - m * m;
        float r = rsqrtf(v + 1e-5f);
        if (dbl) r *= rsqrtf(v / (v + 1e-5f) + 1e-5f);   // exact LN(LN(x)) fold
        ms[tid] = m; rs[tid] = r;
    }
    __syncthreads();
}
__device__ __forceinline__ void ln_apply64(short* buf, int tid,
                                           const float* ms, const float* rs) {
    int row = tid >> 3, p = tid & 7;
    float m = ms[row], r = rs[row];
    bf16x8* bp = (bf16x8*)(buf + row * STS + p * 16);
#pragma unroll
    for (int q8 = 0; q8 < 2; ++q8) {
        bf16x8 x = bp[q8]; bf16x8 o;
#pragma unroll
        for (int e = 0; e < 8; ++e) o[e] = bfc((b2f(x[e]) - m) * r);
        bp[q8] = o;
    }
    __syncthreads();
}

// ---------------- kernel 4: 4 frames/block, MFMA attention + FFN -------------
__global__ __launch_bounds__(512, 4) void k_frames(
    const short* __restrict__ kvB,    const float* __restrict__ text,
    const float* __restrict__ kf,     const float* __restrict__ vf,
    const short* __restrict__ W1T,    const short* __restrict__ W2T,
    const short* __restrict__ WQT,    const short* __restrict__ WQFT,
    float* __restrict__ out) {
    __shared__ __align__(16) short sT[MROWS * STS];     // state (t / z / x / z2)
    __shared__ __align__(16) short sX[MROWS * STS];     // Q / H-chunk / Qf / z3
    __shared__ __align__(16) short sVT[128 * VTS];      // V^T union (dims x keys)
    __shared__ __align__(16) short sPB[8 * 16 * PBS];   // per-wave P; kf/vf/scores at end
    __shared__ float sPa[512], sPb[512];
    __shared__ float sMean[64], sRstd[64];

    const int tid = threadIdx.x;        // 512 = 8 waves
    const int w = tid >> 6;             // wave 0..7
    const int lane = tid & 63;
    const int lq = lane & 15;
    const int quad = lane >> 4;
    const int T0 = blockIdx.x * FPB;

    // init: t rows m = f*16+q <- text[q][:]
    for (int o = tid; o < MROWS * 128; o += 512)
        sT[(o >> 7) * STS + (o & 127)] = bfc(text[((o >> 7) & 15) * 128 + (o & 127)]);
    __syncthreads();

    for (int l = 0; l < 2; ++l) {
        const short* kvK = kvB + (size_t)(2 * l) * ASTRIDE;
        const short* kvV = kvB + (size_t)(2 * l + 1) * ASTRIDE;

        // ---- stage V^T union + LN stats of t (barrier inside covers both) ---
        for (int o = tid; o < UROWS * 128; o += 512) {
            int u = o >> 7, d = o & 127;
            sVT[d * VTS + u] = kvV[(size_t)(T0 + u) * 128 + d];
        }
        ln_stats64(sT, tid, 0, sPa, sPb, sMean, sRstd);

        // ---- Q = LN(t) @ Wq[l] -> sX (LN applied inline on A-fragments) ----
        {
            const short* wq = WQT + (size_t)l * 16384;
            bf16x8 B[4];
#pragma unroll
            for (int ks = 0; ks < 4; ++ks)
                B[ks] = *(const bf16x8*)&wq[(w * 16 + lq) * 128 + ks * 32 + quad * 8];
#pragma unroll
            for (int mt = 0; mt < 4; ++mt) {
                int row = mt * 16 + lq;
                float m = sMean[row], r = sRstd[row];
                f32x4 acc = {0.f, 0.f, 0.f, 0.f};
#pragma unroll
                for (int ks = 0; ks < 4; ++ks) {
                    bf16x8 t8 = *(const bf16x8*)&sT[row * STS + ks * 32 + quad * 8];
                    bf16x8 a8;
#pragma unroll
                    for (int e = 0; e < 8; ++e) a8[e] = bfc((b2f(t8[e]) - m) * r);
                    acc = MFMA16(a8, B[ks], acc);
                }
#pragma unroll
                for (int r4 = 0; r4 < 4; ++r4)
                    sX[(mt * 16 + quad * 4 + r4) * STS + w * 16 + lq] = bfc(acc[r4]);
            }
        }
        __syncthreads();

        // ---- attention: wave pair (2f, 2f+1) handles frame f, 4 heads each --
        {
            const int f = w >> 1;
            const int hg = (w & 1) * 4;
            short* Pb = sPB + w * 16 * PBS;
            bf16x8 zv = {};
            for (int hh = 0; hh < 4; ++hh) {
                const int h = hg + hh;
                bf16x8 aq;
                {
                    bf16x8 t8 = *(const bf16x8*)&sX[(f * 16 + lq) * STS + h * 16 + (quad & 1) * 8];
                    aq = (quad < 2) ? t8 : zv;
                }
                f32x4 sc4[4];
#pragma unroll
                for (int kt = 0; kt < 4; ++kt) {
                    bf16x8 bk = *(const bf16x8*)&kvK[(size_t)(T0 + f + kt * 16 + lq) * 128 + h * 16 + (quad & 1) * 8];
                    bk = (quad < 2) ? bk : zv;
                    f32x4 z4 = {0.f, 0.f, 0.f, 0.f};
                    sc4[kt] = MFMA16(aq, bk, z4);
                }
                // softmax in C-layout registers; keep fp32 P values
                float pr[4][4];   // [r][kt]
#pragma unroll
                for (int r = 0; r < 4; ++r) {
                    float a0 = sc4[0][r] * 0.25f, a1 = sc4[1][r] * 0.25f;
                    float a2 = sc4[2][r] * 0.25f, a3 = sc4[3][r] * 0.25f;
                    float mx = fmaxf(fmaxf(a0, a1), fmaxf(a2, a3));
                    mx = fmaxf(mx, __shfl_xor(mx, 1));
                    mx = fmaxf(mx, __shfl_xor(mx, 2));
                    mx = fmaxf(mx, __shfl_xor(mx, 4));
                    mx = fmaxf(mx, __shfl_xor(mx, 8));
                    float e0 = expf(a0 - mx), e1 = expf(a1 - mx);
                    float e2 = expf(a2 - mx), e3 = expf(a3 - mx);
                    float s = e0 + e1 + e2 + e3;
                    s += __shfl_xor(s, 1);
                    s += __shfl_xor(s, 2);
                    s += __shfl_xor(s, 4);
                    s += __shfl_xor(s, 8);
                    float inv = 1.f / s;
                    pr[r][0] = e0 * inv; pr[r][1] = e1 * inv;
                    pr[r][2] = e2 * inv; pr[r][3] = e3 * inv;
                }
                // V^T window fragments once (register-resident across hi/lo passes)
                const short* vr = &sVT[(h * 16 + lq) * VTS];
                int4 v0 = *(const int4*)&vr[quad * 8];
                int4 v1 = *(const int4*)&vr[quad * 8 + 8];
                int4 u0 = *(const int4*)&vr[32 + quad * 8];
                int4 u1 = *(const int4*)&vr[32 + quad * 8 + 8];
                bf16x8 b0 = shiftf(v0, v1, f);
                bf16x8 b1 = shiftf(u0, u1, f);
                // PV with hi+lo bf16 split of P (restores ~fp32 precision).
                // Wave-private Pb: write->read->write->read ordering is enforced
                // by the compiler's lgkmcnt waits; no __syncthreads needed.
                f32x4 ctx = {0.f, 0.f, 0.f, 0.f};
#pragma unroll
                for (int pass = 0; pass < 2; ++pass) {
#pragma unroll
                    for (int r = 0; r < 4; ++r)
#pragma unroll
                        for (int kt = 0; kt < 4; ++kt) {
                            float p = pr[r][kt];
                            short hi = bfc(p);
                            short v16 = pass == 0 ? hi : bfc(p - b2f(hi));
                            Pb[(quad * 4 + r) * PBS + kt * 16 + lq] = v16;
                        }
                    bf16x8 p0 = *(const bf16x8*)&Pb[lq * PBS + quad * 8];
                    bf16x8 p1 = *(const bf16x8*)&Pb[lq * PBS + 32 + quad * 8];
                    ctx = MFMA16(p0, b0, ctx);
                    ctx = MFMA16(p1, b1, ctx);
                }
                // z = ctx + tq  (tq recomputed from t + stats, fp32)
#pragma unroll
                for (int r = 0; r < 4; ++r) {
                    int row = f * 16 + quad * 4 + r;
                    int col = h * 16 + lq;
                    float tq = (b2f(sT[row * STS + col]) - sMean[row]) * sRstd[row];
                    sT[row * STS + col] = bfc(ctx[r] + tq);
                }
            }
        }
        __syncthreads();

        // ---- x = LN(LN(z)) in place ----
        ln_stats64(sT, tid, 1, sPa, sPb, sMean, sRstd);
        ln_apply64(sT, tid, sMean, sRstd);

        // ---- FFN: z2 = relu(x@W1)@W2 + x -> sT ----
        {
            const short* w1p = W1T + (size_t)l * 262144;
            const short* w2p = W2T + (size_t)l * 262144;
            bf16x8 XA[4][4];
#pragma unroll
            for (int mt = 0; mt < 4; ++mt)
#pragma unroll
                for (int ks = 0; ks < 4; ++ks)
                    XA[mt][ks] = *(const bf16x8*)&sT[(mt * 16 + lq) * STS + ks * 32 + quad * 8];
            f32x4 yacc[4];
#pragma unroll
            for (int mt = 0; mt < 4; ++mt) yacc[mt] = (f32x4){0.f, 0.f, 0.f, 0.f};
            for (int c = 0; c < 16; ++c) {
                // GEMM1: wave w -> H cols c*128 + w*16 .. +15
                {
                    f32x4 hacc[4];
#pragma unroll
                    for (int mt = 0; mt < 4; ++mt) hacc[mt] = (f32x4){0.f, 0.f, 0.f, 0.f};
#pragma unroll
                    for (int ks = 0; ks < 4; ++ks) {
                        bf16x8 B1 = *(const bf16x8*)&w1p[(size_t)(c * 128 + w * 16 + lq) * 128 + ks * 32 + quad * 8];
#pragma unroll
                        for (int mt = 0; mt < 4; ++mt) hacc[mt] = MFMA16(XA[mt][ks], B1, hacc[mt]);
                    }
#pragma unroll
                    for (int mt = 0; mt < 4; ++mt)
#pragma unroll
                        for (int r = 0; r < 4; ++r)
                            sX[(mt * 16 + quad * 4 + r) * STS + w * 16 + lq] = bfc(fmaxf(hacc[mt][r], 0.f));
                }
                __syncthreads();
                // GEMM2: wave w -> out cols w*16..+15, accumulate over chunk
#pragma unroll
                for (int ks = 0; ks < 4; ++ks) {
                    bf16x8 B2 = *(const bf16x8*)&w2p[(size_t)(w * 16 + lq) * 2048 + c * 128 + ks * 32 + quad * 8];
#pragma unroll
                    for (int mt = 0; mt < 4; ++mt) {
                        bf16x8 A = *(const bf16x8*)&sX[(mt * 16 + lq) * STS + ks * 32 + quad * 8];
                        yacc[mt] = MFMA16(A, B2, yacc[mt]);
                    }
                }
                __syncthreads();
            }
            // z2 = Y + x
#pragma unroll
            for (int mt = 0; mt < 4; ++mt)
#pragma unroll
                for (int r = 0; r < 4; ++r) {
                    int row = mt * 16 + quad * 4 + r;
                    int col = w * 16 + lq;
                    sT[row * STS + col] = bfc(yacc[mt][r] + b2f(sT[row * STS + col]));
                }
        }
        __syncthreads();

        // ---- t = LN(z2) in place ----
        ln_stats64(sT, tid, 0, sPa, sPb, sMean, sRstd);
        ln_apply64(sT, tid, sMean, sRstd);
    }

    // ================= final single-head attention (d_q = 128) ==============
    // Qf = t @ Wq_f -> sX
    {
        bf16x8 B[4];
#pragma unroll
        for (int ks = 0; ks < 4; ++ks)
            B[ks] = *(const bf16x8*)&WQFT[(w * 16 + lq) * 128 + ks * 32 + quad * 8];
#pragma unroll
        for (int mt = 0; mt < 4; ++mt) {
            f32x4 acc = {0.f, 0.f, 0.f, 0.f};
#pragma unroll
            for (int ks = 0; ks < 4; ++ks) {
                bf16x8 A = *(const bf16x8*)&sT[(mt * 16 + lq) * STS + ks * 32 + quad * 8];
                acc = MFMA16(A, B[ks], acc);
            }
#pragma unroll
            for (int r = 0; r < 4; ++r)
                sX[(mt * 16 + quad * 4 + r) * STS + w * 16 + lq] = bfc(acc[r]);
        }
    }
    // stage kf/vf + score buffer in sPB (dead)
    short* kfL = sPB;
    short* vfL = sPB + 16 * STS;
    float* scF = (float*)(sPB + 2 * 16 * STS);       // [64][17] fp32
    for (int o = tid; o < 2048; o += 512) {
        kfL[(o >> 7) * STS + (o & 127)] = bfc(kf[o]);
        vfL[(o >> 7) * STS + (o & 127)] = bfc(vf[o]);
    }
    __syncthreads();
    // scores[m][k] = Qf[m] . kf[k] / sqrt(128)
    if (tid < 256) {
        int m = tid >> 2, kq = tid & 3;
        float a4[4] = {0.f, 0.f, 0.f, 0.f};
        for (int d8 = 0; d8 < 16; ++d8) {
            bf16x8 qc = *(const bf16x8*)&sX[m * STS + d8 * 8];
            float qf[8];
#pragma unroll
            for (int e = 0; e < 8; ++e) qf[e] = b2f(qc[e]);
#pragma unroll
            for (int k = 0; k < 4; ++k) {
                bf16x8 kc = *(const bf16x8*)&kfL[(kq * 4 + k) * STS + d8 * 8];
#pragma unroll
                for (int e = 0; e < 8; ++e) a4[k] += qf[e] * b2f(kc[e]);
            }
        }
#pragma unroll
        for (int k = 0; k < 4; ++k)
            scF[m * 17 + kq * 4 + k] = a4[k] * 0.08838834764831845f;
    }
    __syncthreads();
    if (tid < 64) {
        float* row = scF + tid * 17;
        float mx = row[0];
#pragma unroll
        for (int k = 1; k < 16; ++k) mx = fmaxf(mx, row[k]);
        float sum = 0.f;
#pragma unroll
        for (int k = 0; k < 16; ++k) { float e = expf(row[k] - mx); row[k] = e; sum += e; }
        float inv = 1.f / sum;
#pragma unroll
        for (int k = 0; k < 16; ++k) row[k] *= inv;
    }
    __syncthreads();
    // z3 = attn @ vf + t -> sX
    {
        int jj = tid & 127, rr0 = tid >> 7;
        float vv[16];
#pragma unroll
        for (int k = 0; k < 16; ++k) vv[k] = b2f(vfL[k * STS + jj]);
#pragma unroll 4
        for (int rr = 0; rr < 16; ++rr) {
            int row = rr0 + 4 * rr;
            float acc = 0.f;
#pragma unroll
            for (int k = 0; k < 16; ++k) acc += scF[row * 17 + k] * vv[k];
            sX[row * STS + jj] = bfc(acc + b2f(sT[row * STS + jj]));
        }
    }
    __syncthreads();
    // out = LN(z3), fp32
    ln_stats64(sX, tid, 0, sPa, sPb, sMean, sRstd);
    for (int o = tid; o < MROWS * 128; o += 512) {
        int r = o >> 7;
        out[(size_t)T0 * 2048 + o] = (b2f(sX[r * STS + (o & 127)]) - sMean[r]) * sRstd[r];
    }
}

extern "C" void kernel_launch(void* const* d_in, const int* in_sizes, int n_in,
                              void* d_out, int out_size, void* d_ws, size_t ws_size,
                              hipStream_t stream) {
    const float* g      = (const float*)d_in[0];
    const float* lf     = (const float*)d_in[1];
    const float* Wvis   = (const float*)d_in[2];
    const float* Wtxt   = (const float*)d_in[3];
    const float* Wq_enc = (const float*)d_in[4];
    const float* Wk_enc = (const float*)d_in[5];
    const float* Wv_enc = (const float*)d_in[6];
    const float* W1f    = (const float*)d_in[7];
    const float* W2f    = (const float*)d_in[8];
    const float* Wqf    = (const float*)d_in[9];
    const float* Wkf    = (const float*)d_in[10];
    const float* Wvf    = (const float*)d_in[11];
    float* out = (float*)d_out;
    float* ws  = (float*)d_ws;

    float* visn = ws + OFF_VISN;
    short* kvB  = (short*)(ws + OFF_KV);
    float* text = ws + OFF_TEXT;
    float* kfp  = ws + OFF_KF;
    float* vfp  = ws + OFF_VF;
    short* W1T  = (short*)(ws + OFF_W1T);
    short* W2T  = (short*)(ws + OFF_W2T);
    short* WQT  = (short*)(ws + OFF_WQT);
    short* WQFT = (short*)(ws + OFF_WQFT);

    // zero the whole bf16 kv region (covers the 63 pad rows; interior rewritten)
    hipMemsetAsync(kvB, 0, (size_t)4 * ASTRIDE * sizeof(short), stream);

    k_wcvt  <<<dim3(1024, 7), dim3(256), 0, stream>>>(Wq_enc, W1f, W2f, Wqf, W1T, W2T, WQT, WQFT);
    k_visln <<<dim3(TFRAMES / 16), dim3(128), 0, stream>>>(lf, Wvis, visn);
    k_kvproj<<<dim3(TFRAMES / 16, 4), dim3(128), 0, stream>>>(visn, Wk_enc, Wv_enc, kvB);
    k_text  <<<dim3(NG), dim3(128), 0, stream>>>(g, Wtxt, Wkf, Wvf, text, kfp, vfp);
    k_frames<<<dim3(TFRAMES / FPB), dim3(512), 0, stream>>>(kvB, text, kfp, vfp, W1T, W2T, WQT, WQFT, out);
}

// Round 7
// 633.498 us; speedup vs baseline: 10.2156x; 1.1442x over previous
//
#include <hip/hip_runtime.h>
#include <math.h>

#define TFRAMES 4096
#define DM 128
#define LQ 64
#define NG 16
#define NH 8
#define DQH 16
#define FD 2048
#define GFD 512
#define PAD 63
#define KVROWS (TFRAMES + PAD)      /* 4159 */
#define ASTRIDE (KVROWS * DM)       /* 532352 SHORTS per bf16 K/V array */
#define FPB 4                       /* frames per block */
#define MROWS (FPB * NG)            /* 64 state rows per block */
#define STS 136                     /* state row stride (shorts, mult of 8) */
#define VTS 72                      /* V^T row stride (shorts) */
#define PBS 72                      /* P buffer row stride (shorts) */
#define UROWS (LQ + FPB - 1)        /* 67 K/V union rows */

/* ws layout (floats). Region [0, 524288) holds the transposed hi/lo weights
   (replaces the old visn buffer); kv bf16 follows. */
#define OFF_WVH  0                                 /* Wvis^T hi: 128x2048 sh = 131072 fl */
#define OFF_WVL  131072
#define OFF_WKVH 262144                            /* Wk/Wv^T hi: 4x16384 sh = 32768 fl */
#define OFF_WKVL 294912
#define OFF_KV   (TFRAMES * DM)                    /* 524288 */
#define OFF_TEXT (OFF_KV + 2 * ASTRIDE)
#define OFF_KF   (OFF_TEXT + NG * DM)
#define OFF_VF   (OFF_KF + NG * DM)
#define OFF_W1T  (OFF_VF + NG * DM)
#define OFF_W2T  (OFF_W1T + 262144)
#define OFF_WQT  (OFF_W2T + 262144)
#define OFF_WQFT (OFF_WQT + 16384)

typedef __attribute__((ext_vector_type(8))) short bf16x8;
typedef __attribute__((ext_vector_type(4))) float f32x4;
#define MFMA16(a, b, c) __builtin_amdgcn_mfma_f32_16x16x32_bf16(a, b, c, 0, 0, 0)

__device__ __forceinline__ short bfc(float x) {
    union { float f; unsigned u; } v; v.f = x;
    unsigned r = v.u + 0x7fffu + ((v.u >> 16) & 1u);   // RNE
    return (short)(r >> 16);
}
__device__ __forceinline__ float b2f(short s) {
    union { unsigned u; float f; } v;
    v.u = ((unsigned)(unsigned short)s) << 16;
    return v.f;
}
// Extract 8 shorts starting at short-offset f (0..3) from the 12-short window
// {a.x..a.w, b.x, b.y}. v_alignbit_b32 shift is 5-bit (wraps at 32!), so split
// f into a word offset (wo = f>>1, uniform select) + residual 0/16-bit shift.
__device__ __forceinline__ bf16x8 shiftf(int4 a, int4 b, int f) {
    const int wo = f >> 1;
    const int sh = (f & 1) * 16;
    int w0 = wo ? a.y : a.x;
    int w1 = wo ? a.z : a.y;
    int w2 = wo ? a.w : a.z;
    int w3 = wo ? b.x : a.w;
    int w4 = wo ? b.y : b.x;
    int o0 = __builtin_amdgcn_alignbit(w1, w0, sh);
    int o1 = __builtin_amdgcn_alignbit(w2, w1, sh);
    int o2 = __builtin_amdgcn_alignbit(w3, w2, sh);
    int o3 = __builtin_amdgcn_alignbit(w4, w3, sh);
    int4 o = {o0, o1, o2, o3};
    return *(bf16x8*)&o;
}

// -------- kernel W1: bf16 transposed weights (+ hi/lo Wk/Wv) -----------------
__global__ __launch_bounds__(256) void k_wcvt(const float* __restrict__ Wq_enc,
                                              const float* __restrict__ W1f,
                                              const float* __restrict__ W2f,
                                              const float* __restrict__ Wqf,
                                              const float* __restrict__ Wk_enc,
                                              const float* __restrict__ Wv_enc,
                                              short* __restrict__ W1T,
                                              short* __restrict__ W2T,
                                              short* __restrict__ WQT,
                                              short* __restrict__ WQFT,
                                              short* __restrict__ WKVH,
                                              short* __restrict__ WKVL) {
    const int t = blockIdx.x * 256 + threadIdx.x;
    const int gsel = blockIdx.y;
    if (gsel < 2) {
        int n = t >> 7, k = t & 127;
        W1T[gsel * 262144 + t] = bfc(W1f[(size_t)gsel * 262144 + (size_t)k * FD + n]);
    } else if (gsel < 4) {
        int l = gsel - 2;
        int n = t >> 11, k = t & 2047;
        W2T[l * 262144 + t] = bfc(W2f[(size_t)l * 262144 + (size_t)k * DM + n]);
    } else if (gsel < 6) {
        int l = gsel - 4;
        if (t < 16384) {
            int n = t >> 7, k = t & 127;
            WQT[l * 16384 + t] = bfc(Wq_enc[(size_t)l * 16384 + k * DM + n]);
        }
    } else if (gsel == 6) {
        if (t < 16384) {
            int n = t >> 7, k = t & 127;
            WQFT[t] = bfc(Wqf[(size_t)k * DM + n]);
        }
    } else {
        if (t < 65536) {                 // hi/lo transposed Wk/Wv (a = 2l + isV)
            int a = t >> 14, rem = t & 16383;
            int n = rem >> 7, k = rem & 127;
            const float* src = ((a & 1) ? Wv_enc : Wk_enc) + (size_t)(a >> 1) * 16384;
            float v = src[k * 128 + n];
            short hi = bfc(v);
            WKVH[t] = hi;
            WKVL[t] = bfc(v - b2f(hi));
        }
    }
}

// -------- kernel W2: Wvis^T hi/lo via coalesced LDS tile transpose -----------
__global__ __launch_bounds__(256) void k_wvt(const float* __restrict__ Wvis,
                                             short* __restrict__ WVH,
                                             short* __restrict__ WVL) {
    __shared__ float tile[64][65];
    const int tid = threadIdx.x;
    const int k0 = blockIdx.x * 64;     // 32 tiles along K=2048
    const int n0 = blockIdx.y * 64;     // 2 tiles along N=128
    for (int o = tid; o < 64 * 64; o += 256) {
        int r = o >> 6, c = o & 63;
        tile[r][c] = Wvis[(size_t)(k0 + r) * DM + n0 + c];
    }
    __syncthreads();
    for (int o = tid; o < 64 * 64; o += 256) {
        int rn = o >> 6, ck = o & 63;
        float v = tile[ck][rn];
        short hi = bfc(v);
        WVH[(size_t)(n0 + rn) * FD + k0 + ck] = hi;
        WVL[(size_t)(n0 + rn) * FD + k0 + ck] = bfc(v - b2f(hi));
    }
}

// -------- kernel P: visual=lf@Wvis, LN, K/V=visn@Wk/Wv — all MFMA, hi/lo -----
// 3-pass hi/lo (AhBh + AlBh + AhBl) keeps ~fp32 accuracy end to end.
__global__ __launch_bounds__(256) void k_viskv(const float* __restrict__ lf,
                                               const short* __restrict__ WVH,
                                               const short* __restrict__ WVL,
                                               const short* __restrict__ WKVH,
                                               const short* __restrict__ WKVL,
                                               short* __restrict__ kvB) {
    __shared__ __align__(16) char smem[17408 + 4352];   // Ah|Al  /  vis | Vh | Vl
    __shared__ float sPa[256], sPb[256], sMean[16], sRstd[16];
    short* Ah = (short*)smem;                 // [16][136] bf16 (4352 B)
    short* Al = (short*)(smem + 4352);        // [16][136]
    float* vis = (float*)smem;                // [16][132] fp32 (8448 B, overlays Ah/Al)
    short* Vh = (short*)(smem + 8704);        // [16][136]
    short* Vl = (short*)(smem + 13056);       // [16][136]

    const int tid = threadIdx.x;              // 256 = 4 waves
    const int w = tid >> 6;
    const int lane = tid & 63;
    const int lq = lane & 15;
    const int quad = lane >> 4;
    const int r0 = blockIdx.x * 16;           // 256 blocks x 16 rows

    // ---- phase 1: visual = lf @ Wvis  (K=2048 in 16 chunks of 128) ----
    f32x4 acc[2];     // wave w owns out cols w*32 .. w*32+31 (2 n-tiles)
    acc[0] = (f32x4){0.f, 0.f, 0.f, 0.f};
    acc[1] = (f32x4){0.f, 0.f, 0.f, 0.f};
    for (int c = 0; c < 16; ++c) {
        __syncthreads();                      // prior MFMA reads done before overwrite
        for (int o = tid; o < 16 * 128; o += 256) {
            int r = o >> 7, j = o & 127;
            float v = lf[(size_t)(r0 + r) * FD + c * 128 + j];
            short hi = bfc(v);
            Ah[r * 136 + j] = hi;
            Al[r * 136 + j] = bfc(v - b2f(hi));
        }
        __syncthreads();
#pragma unroll
        for (int ks = 0; ks < 4; ++ks) {
            bf16x8 ah = *(const bf16x8*)&Ah[lq * 136 + ks * 32 + quad * 8];
            bf16x8 al = *(const bf16x8*)&Al[lq * 136 + ks * 32 + quad * 8];
#pragma unroll
            for (int nt = 0; nt < 2; ++nt) {
                const size_t bo = (size_t)(w * 32 + nt * 16 + lq) * FD + c * 128 + ks * 32 + quad * 8;
                bf16x8 bh = *(const bf16x8*)&WVH[bo];
                bf16x8 bl = *(const bf16x8*)&WVL[bo];
                acc[nt] = MFMA16(ah, bh, acc[nt]);
                acc[nt] = MFMA16(al, bh, acc[nt]);
                acc[nt] = MFMA16(ah, bl, acc[nt]);
            }
        }
    }
    __syncthreads();
    // C-layout -> vis[row][col] fp32 (row = quad*4+r, col = w*32+nt*16+lq)
#pragma unroll
    for (int nt = 0; nt < 2; ++nt)
#pragma unroll
        for (int r = 0; r < 4; ++r)
            vis[(quad * 4 + r) * 132 + w * 32 + nt * 16 + lq] = acc[nt][r];
    __syncthreads();

    // ---- phase 2: LN over 128 cols per row; visn -> hi/lo bf16 ----
    {
        int row = tid >> 4, p = tid & 15;     // 8 cols per thread
        float s = 0.f, s2 = 0.f;
#pragma unroll
        for (int k = 0; k < 8; ++k) { float v = vis[row * 132 + p * 8 + k]; s += v; s2 += v * v; }
        sPa[tid] = s; sPb[tid] = s2;
    }
    __syncthreads();
    if (tid < 16) {
        float s = 0.f, s2 = 0.f;
#pragma unroll
        for (int p = 0; p < 16; ++p) { s += sPa[tid * 16 + p]; s2 += sPb[tid * 16 + p]; }
        float m = s * (1.f / 128.f);
        float v = s2 * (1.f / 128.f) - m * m;
        sMean[tid] = m; sRstd[tid] = rsqrtf(v + 1e-5f);
    }
    __syncthreads();
    for (int o = tid; o < 16 * 128; o += 256) {
        int r = o >> 7, j = o & 127;
        float v = (vis[r * 132 + j] - sMean[r]) * sRstd[r];
        short hi = bfc(v);
        Vh[r * 136 + j] = hi;
        Vl[r * 136 + j] = bfc(v - b2f(hi));
    }
    __syncthreads();

    // ---- phase 3: K/V = visn @ Wk/Wv per array (K=128), bf16 out ----
    for (int a = 0; a < 4; ++a) {
        f32x4 ka[2];
        ka[0] = (f32x4){0.f, 0.f, 0.f, 0.f};
        ka[1] = (f32x4){0.f, 0.f, 0.f, 0.f};
#pragma unroll
        for (int ks = 0; ks < 4; ++ks) {
            bf16x8 ah = *(const bf16x8*)&Vh[lq * 136 + ks * 32 + quad * 8];
            bf16x8 al = *(const bf16x8*)&Vl[lq * 136 + ks * 32 + quad * 8];
#pragma unroll
            for (int nt = 0; nt < 2; ++nt) {
                const size_t bo = (size_t)a * 16384 + (size_t)(w * 32 + nt * 16 + lq) * 128 + ks * 32 + quad * 8;
                bf16x8 bh = *(const bf16x8*)&WKVH[bo];
                bf16x8 bl = *(const bf16x8*)&WKVL[bo];
                ka[nt] = MFMA16(ah, bh, ka[nt]);
                ka[nt] = MFMA16(al, bh, ka[nt]);
                ka[nt] = MFMA16(ah, bl, ka[nt]);
            }
        }
#pragma unroll
        for (int nt = 0; nt < 2; ++nt)
#pragma unroll
            for (int r = 0; r < 4; ++r)
                kvB[(size_t)a * ASTRIDE + (size_t)(PAD + r0 + quad * 4 + r) * DM + w * 32 + nt * 16 + lq]
                    = bfc(ka[nt][r]);
    }
}

// -------- kernel 3: text = g @ W_txt ; Kf = text @ Wk_f ; Vf = text @ Wv_f ---
__global__ __launch_bounds__(128) void k_text(const float* __restrict__ g,
                                              const float* __restrict__ Wtxt,
                                              const float* __restrict__ Wkf,
                                              const float* __restrict__ Wvf,
                                              float* __restrict__ text,
                                              float* __restrict__ kf,
                                              float* __restrict__ vf) {
    __shared__ float gs[GFD];
    __shared__ float tr[DM];
    const int r = blockIdx.x;
    const int tid = threadIdx.x;
    for (int i = tid; i < GFD; i += 128) gs[i] = g[(size_t)r * GFD + i];
    __syncthreads();
    float acc = 0.f;
    for (int k = 0; k < GFD; ++k) acc += gs[k] * Wtxt[(size_t)k * DM + tid];
    tr[tid] = acc;
    text[(size_t)r * DM + tid] = acc;
    __syncthreads();
    float a1 = 0.f, a2 = 0.f;
    for (int k = 0; k < DM; ++k) {
        float x = tr[k];
        a1 += x * Wkf[(size_t)k * DM + tid];
        a2 += x * Wvf[(size_t)k * DM + tid];
    }
    kf[(size_t)r * DM + tid] = a1;
    vf[(size_t)r * DM + tid] = a2;
}

// ---------------- LN helpers for [64][STS] bf16 LDS tile ---------------------
__device__ __forceinline__ void ln_stats64(const short* buf, int tid, int dbl,
                                           float* pa, float* pb, float* ms, float* rs) {
    {
        int row = tid >> 3, p = tid & 7;
        const bf16x8* bp = (const bf16x8*)(buf + row * STS + p * 16);
        float s = 0.f, s2 = 0.f;
#pragma unroll
        for (int q8 = 0; q8 < 2; ++q8) {
            bf16x8 x = bp[q8];
#pragma unroll
            for (int e = 0; e < 8; ++e) { float v = b2f(x[e]); s += v; s2 += v * v; }
        }
        pa[tid] = s; pb[tid] = s2;
    }
    __syncthreads();
    if (tid < 64) {
        float ss = 0.f, ss2 = 0.f;
#pragma unroll
        for (int p2 = 0; p2 < 8; ++p2) { ss += pa[tid * 8 + p2]; ss2 += pb[tid * 8 + p2]; }
        float m = ss * (1.f / 128.f);
        float v = ss2 * (1.f / 128.f) - m * m;
        float r = rsqrtf(v + 1e-5f);
        if (dbl) r *= rsqrtf(v / (v + 1e-5f) + 1e-5f);   // exact LN(LN(x)) fold
        ms[tid] = m; rs[tid] = r;
    }
    __syncthreads();
}
__device__ __forceinline__ void ln_apply64(short* buf, int tid,
                                           const float* ms, const float* rs) {
    int row = tid >> 3, p = tid & 7;
    float m = ms[row], r = rs[row];
    bf16x8* bp = (bf16x8*)(buf + row * STS + p * 16);
#pragma unroll
    for (int q8 = 0; q8 < 2; ++q8) {
        bf16x8 x = bp[q8]; bf16x8 o;
#pragma unroll
        for (int e = 0; e < 8; ++e) o[e] = bfc((b2f(x[e]) - m) * r);
        bp[q8] = o;
    }
    __syncthreads();
}

// ---------------- kernel 4: 4 frames/block, MFMA attention + FFN -------------
__global__ __launch_bounds__(512, 4) void k_frames(
    const short* __restrict__ kvB,    const float* __restrict__ text,
    const float* __restrict__ kf,     const float* __restrict__ vf,
    const short* __restrict__ W1T,    const short* __restrict__ W2T,
    const short* __restrict__ WQT,    const short* __restrict__ WQFT,
    float* __restrict__ out) {
    __shared__ __align__(16) short sT[MROWS * STS];     // state (t / z / x / z2)
    __shared__ __align__(16) short sX[MROWS * STS];     // Q / H-chunk / Qf / z3
    __shared__ __align__(16) short sVT[128 * VTS];      // V^T union (dims x keys)
    __shared__ __align__(16) short sPB[8 * 16 * PBS];   // per-wave P; kf/vf/scores at end
    __shared__ float sPa[512], sPb[512];
    __shared__ float sMean[64], sRstd[64];

    const int tid = threadIdx.x;        // 512 = 8 waves
    const int w = tid >> 6;             // wave 0..7
    const int lane = tid & 63;
    const int lq = lane & 15;
    const int quad = lane >> 4;
    const int T0 = blockIdx.x * FPB;

    // init: t rows m = f*16+q <- text[q][:]
    for (int o = tid; o < MROWS * 128; o += 512)
        sT[(o >> 7) * STS + (o & 127)] = bfc(text[((o >> 7) & 15) * 128 + (o & 127)]);
    __syncthreads();

    for (int l = 0; l < 2; ++l) {
        const short* kvK = kvB + (size_t)(2 * l) * ASTRIDE;
        const short* kvV = kvB + (size_t)(2 * l + 1) * ASTRIDE;

        // ---- stage V^T union + LN stats of t (barrier inside covers both) ---
        for (int o = tid; o < UROWS * 128; o += 512) {
            int u = o >> 7, d = o & 127;
            sVT[d * VTS + u] = kvV[(size_t)(T0 + u) * 128 + d];
        }
        ln_stats64(sT, tid, 0, sPa, sPb, sMean, sRstd);

        // ---- Q = LN(t) @ Wq[l] -> sX (LN applied inline on A-fragments) ----
        {
            const short* wq = WQT + (size_t)l * 16384;
            bf16x8 B[4];
#pragma unroll
            for (int ks = 0; ks < 4; ++ks)
                B[ks] = *(const bf16x8*)&wq[(w * 16 + lq) * 128 + ks * 32 + quad * 8];
#pragma unroll
            for (int mt = 0; mt < 4; ++mt) {
                int row = mt * 16 + lq;
                float m = sMean[row], r = sRstd[row];
                f32x4 acc = {0.f, 0.f, 0.f, 0.f};
#pragma unroll
                for (int ks = 0; ks < 4; ++ks) {
                    bf16x8 t8 = *(const bf16x8*)&sT[row * STS + ks * 32 + quad * 8];
                    bf16x8 a8;
#pragma unroll
                    for (int e = 0; e < 8; ++e) a8[e] = bfc((b2f(t8[e]) - m) * r);
                    acc = MFMA16(a8, B[ks], acc);
                }
#pragma unroll
                for (int r4 = 0; r4 < 4; ++r4)
                    sX[(mt * 16 + quad * 4 + r4) * STS + w * 16 + lq] = bfc(acc[r4]);
            }
        }
        __syncthreads();

        // ---- attention: wave pair (2f, 2f+1) handles frame f, 4 heads each --
        {
            const int f = w >> 1;
            const int hg = (w & 1) * 4;
            short* Pb = sPB + w * 16 * PBS;
            bf16x8 zv = {};
            for (int hh = 0; hh < 4; ++hh) {
                const int h = hg + hh;
                bf16x8 aq;
                {
                    bf16x8 t8 = *(const bf16x8*)&sX[(f * 16 + lq) * STS + h * 16 + (quad & 1) * 8];
                    aq = (quad < 2) ? t8 : zv;
                }
                f32x4 sc4[4];
#pragma unroll
                for (int kt = 0; kt < 4; ++kt) {
                    bf16x8 bk = *(const bf16x8*)&kvK[(size_t)(T0 + f + kt * 16 + lq) * 128 + h * 16 + (quad & 1) * 8];
                    bk = (quad < 2) ? bk : zv;
                    f32x4 z4 = {0.f, 0.f, 0.f, 0.f};
                    sc4[kt] = MFMA16(aq, bk, z4);
                }
                // softmax in C-layout registers; keep fp32 P values
                float pr[4][4];   // [r][kt]
#pragma unroll
                for (int r = 0; r < 4; ++r) {
                    float a0 = sc4[0][r] * 0.25f, a1 = sc4[1][r] * 0.25f;
                    float a2 = sc4[2][r] * 0.25f, a3 = sc4[3][r] * 0.25f;
                    float mx = fmaxf(fmaxf(a0, a1), fmaxf(a2, a3));
                    mx = fmaxf(mx, __shfl_xor(mx, 1));
                    mx = fmaxf(mx, __shfl_xor(mx, 2));
                    mx = fmaxf(mx, __shfl_xor(mx, 4));
                    mx = fmaxf(mx, __shfl_xor(mx, 8));
                    float e0 = expf(a0 - mx), e1 = expf(a1 - mx);
                    float e2 = expf(a2 - mx), e3 = expf(a3 - mx);
                    float s = e0 + e1 + e2 + e3;
                    s += __shfl_xor(s, 1);
                    s += __shfl_xor(s, 2);
                    s += __shfl_xor(s, 4);
                    s += __shfl_xor(s, 8);
                    float inv = 1.f / s;
                    pr[r][0] = e0 * inv; pr[r][1] = e1 * inv;
                    pr[r][2] = e2 * inv; pr[r][3] = e3 * inv;
                }
                // V^T window fragments once (register-resident across hi/lo passes)
                const short* vr = &sVT[(h * 16 + lq) * VTS];
                int4 v0 = *(const int4*)&vr[quad * 8];
                int4 v1 = *(const int4*)&vr[quad * 8 + 8];
                int4 u0 = *(const int4*)&vr[32 + quad * 8];
                int4 u1 = *(const int4*)&vr[32 + quad * 8 + 8];
                bf16x8 b0 = shiftf(v0, v1, f);
                bf16x8 b1 = shiftf(u0, u1, f);
                // PV with hi+lo bf16 split of P (extra precision margin).
                f32x4 ctx = {0.f, 0.f, 0.f, 0.f};
#pragma unroll
                for (int pass = 0; pass < 2; ++pass) {
#pragma unroll
                    for (int r = 0; r < 4; ++r)
#pragma unroll
                        for (int kt = 0; kt < 4; ++kt) {
                            float p = pr[r][kt];
                            short hi = bfc(p);
                            short v16 = pass == 0 ? hi : bfc(p - b2f(hi));
                            Pb[(quad * 4 + r) * PBS + kt * 16 + lq] = v16;
                        }
                    bf16x8 p0 = *(const bf16x8*)&Pb[lq * PBS + quad * 8];
                    bf16x8 p1 = *(const bf16x8*)&Pb[lq * PBS + 32 + quad * 8];
                    ctx = MFMA16(p0, b0, ctx);
                    ctx = MFMA16(p1, b1, ctx);
                }
                // z = ctx + tq  (tq recomputed from t + stats, fp32)
#pragma unroll
                for (int r = 0; r < 4; ++r) {
                    int row = f * 16 + quad * 4 + r;
                    int col = h * 16 + lq;
                    float tq = (b2f(sT[row * STS + col]) - sMean[row]) * sRstd[row];
                    sT[row * STS + col] = bfc(ctx[r] + tq);
                }
            }
        }
        __syncthreads();

        // ---- x = LN(LN(z)) in place ----
        ln_stats64(sT, tid, 1, sPa, sPb, sMean, sRstd);
        ln_apply64(sT, tid, sMean, sRstd);

        // ---- FFN: z2 = relu(x@W1)@W2 + x -> sT ----
        {
            const short* w1p = W1T + (size_t)l * 262144;
            const short* w2p = W2T + (size_t)l * 262144;
            bf16x8 XA[4][4];
#pragma unroll
            for (int mt = 0; mt < 4; ++mt)
#pragma unroll
                for (int ks = 0; ks < 4; ++ks)
                    XA[mt][ks] = *(const bf16x8*)&sT[(mt * 16 + lq) * STS + ks * 32 + quad * 8];
            f32x4 yacc[4];
#pragma unroll
            for (int mt = 0; mt < 4; ++mt) yacc[mt] = (f32x4){0.f, 0.f, 0.f, 0.f};
            for (int c = 0; c < 16; ++c) {
                // GEMM1: wave w -> H cols c*128 + w*16 .. +15
                {
                    f32x4 hacc[4];
#pragma unroll
                    for (int mt = 0; mt < 4; ++mt) hacc[mt] = (f32x4){0.f, 0.f, 0.f, 0.f};
#pragma unroll
                    for (int ks = 0; ks < 4; ++ks) {
                        bf16x8 B1 = *(const bf16x8*)&w1p[(size_t)(c * 128 + w * 16 + lq) * 128 + ks * 32 + quad * 8];
#pragma unroll
                        for (int mt = 0; mt < 4; ++mt) hacc[mt] = MFMA16(XA[mt][ks], B1, hacc[mt]);
                    }
#pragma unroll
                    for (int mt = 0; mt < 4; ++mt)
#pragma unroll
                        for (int r = 0; r < 4; ++r)
                            sX[(mt * 16 + quad * 4 + r) * STS + w * 16 + lq] = bfc(fmaxf(hacc[mt][r], 0.f));
                }
                __syncthreads();
                // GEMM2: wave w -> out cols w*16..+15, accumulate over chunk
#pragma unroll
                for (int ks = 0; ks < 4; ++ks) {
                    bf16x8 B2 = *(const bf16x8*)&w2p[(size_t)(w * 16 + lq) * 2048 + c * 128 + ks * 32 + quad * 8];
#pragma unroll
                    for (int mt = 0; mt < 4; ++mt) {
                        bf16x8 A = *(const bf16x8*)&sX[(mt * 16 + lq) * STS + ks * 32 + quad * 8];
                        yacc[mt] = MFMA16(A, B2, yacc[mt]);
                    }
                }
                __syncthreads();
            }
            // z2 = Y + x
#pragma unroll
            for (int mt = 0; mt < 4; ++mt)
#pragma unroll
                for (int r = 0; r < 4; ++r) {
                    int row = mt * 16 + quad * 4 + r;
                    int col = w * 16 + lq;
                    sT[row * STS + col] = bfc(yacc[mt][r] + b2f(sT[row * STS + col]));
                }
        }
        __syncthreads();

        // ---- t = LN(z2) in place ----
        ln_stats64(sT, tid, 0, sPa, sPb, sMean, sRstd);
        ln_apply64(sT, tid, sMean, sRstd);
    }

    // ================= final single-head attention (d_q = 128) ==============
    // Qf = t @ Wq_f -> sX
    {
        bf16x8 B[4];
#pragma unroll
        for (int ks = 0; ks < 4; ++ks)
            B[ks] = *(const bf16x8*)&WQFT[(w * 16 + lq) * 128 + ks * 32 + quad * 8];
#pragma unroll
        for (int mt = 0; mt < 4; ++mt) {
            f32x4 acc = {0.f, 0.f, 0.f, 0.f};
#pragma unroll
            for (int ks = 0; ks < 4; ++ks) {
                bf16x8 A = *(const bf16x8*)&sT[(mt * 16 + lq) * STS + ks * 32 + quad * 8];
                acc = MFMA16(A, B[ks], acc);
            }
#pragma unroll
            for (int r = 0; r < 4; ++r)
                sX[(mt * 16 + quad * 4 + r) * STS + w * 16 + lq] = bfc(acc[r]);
        }
    }
    // stage kf/vf + score buffer in sPB (dead)
    short* kfL = sPB;
    short* vfL = sPB + 16 * STS;
    float* scF = (float*)(sPB + 2 * 16 * STS);       // [64][17] fp32
    for (int o = tid; o < 2048; o += 512) {
        kfL[(o >> 7) * STS + (o & 127)] = bfc(kf[o]);
        vfL[(o >> 7) * STS + (o & 127)] = bfc(vf[o]);
    }
    __syncthreads();
    // scores[m][k] = Qf[m] . kf[k] / sqrt(128)
    if (tid < 256) {
        int m = tid >> 2, kq = tid & 3;
        float a4[4] = {0.f, 0.f, 0.f, 0.f};
        for (int d8 = 0; d8 < 16; ++d8) {
            bf16x8 qc = *(const bf16x8*)&sX[m * STS + d8 * 8];
            float qf[8];
#pragma unroll
            for (int e = 0; e < 8; ++e) qf[e] = b2f(qc[e]);
#pragma unroll
            for (int k = 0; k < 4; ++k) {
                bf16x8 kc = *(const bf16x8*)&kfL[(kq * 4 + k) * STS + d8 * 8];
#pragma unroll
                for (int e = 0; e < 8; ++e) a4[k] += qf[e] * b2f(kc[e]);
            }
        }
#pragma unroll
        for (int k = 0; k < 4; ++k)
            scF[m * 17 + kq * 4 + k] = a4[k] * 0.08838834764831845f;
    }
    __syncthreads();
    if (tid < 64) {
        float* row = scF + tid * 17;
        float mx = row[0];
#pragma unroll
        for (int k = 1; k < 16; ++k) mx = fmaxf(mx, row[k]);
        float sum = 0.f;
#pragma unroll
        for (int k = 0; k < 16; ++k) { float e = expf(row[k] - mx); row[k] = e; sum += e; }
        float inv = 1.f / sum;
#pragma unroll
        for (int k = 0; k < 16; ++k) row[k] *= inv;
    }
    __syncthreads();
    // z3 = attn @ vf + t -> sX
    {
        int jj = tid & 127, rr0 = tid >> 7;
        float vv[16];
#pragma unroll
        for (int k = 0; k < 16; ++k) vv[k] = b2f(vfL[k * STS + jj]);
#pragma unroll 4
        for (int rr = 0; rr < 16; ++rr) {
            int row = rr0 + 4 * rr;
            float acc = 0.f;
#pragma unroll
            for (int k = 0; k < 16; ++k) acc += scF[row * 17 + k] * vv[k];
            sX[row * STS + jj] = bfc(acc + b2f(sT[row * STS + jj]));
        }
    }
    __syncthreads();
    // out = LN(z3), fp32
    ln_stats64(sX, tid, 0, sPa, sPb, sMean, sRstd);
    for (int o = tid; o < MROWS * 128; o += 512) {
        int r = o >> 7;
        out[(size_t)T0 * 2048 + o] = (b2f(sX[r * STS + (o & 127)]) - sMean[r]) * sRstd[r];
    }
}

extern "C" void kernel_launch(void* const* d_in, const int* in_sizes, int n_in,
                              void* d_out, int out_size, void* d_ws, size_t ws_size,
                              hipStream_t stream) {
    const float* g      = (const float*)d_in[0];
    const float* lf     = (const float*)d_in[1];
    const float* Wvis   = (const float*)d_in[2];
    const float* Wtxt   = (const float*)d_in[3];
    const float* Wq_enc = (const float*)d_in[4];
    const float* Wk_enc = (const float*)d_in[5];
    const float* Wv_enc = (const float*)d_in[6];
    const float* W1f    = (const float*)d_in[7];
    const float* W2f    = (const float*)d_in[8];
    const float* Wqf    = (const float*)d_in[9];
    const float* Wkf    = (const float*)d_in[10];
    const float* Wvf    = (const float*)d_in[11];
    float* out = (float*)d_out;
    float* ws  = (float*)d_ws;

    short* WVH  = (short*)(ws + OFF_WVH);
    short* WVL  = (short*)(ws + OFF_WVL);
    short* WKVH = (short*)(ws + OFF_WKVH);
    short* WKVL = (short*)(ws + OFF_WKVL);
    short* kvB  = (short*)(ws + OFF_KV);
    float* text = ws + OFF_TEXT;
    float* kfp  = ws + OFF_KF;
    float* vfp  = ws + OFF_VF;
    short* W1T  = (short*)(ws + OFF_W1T);
    short* W2T  = (short*)(ws + OFF_W2T);
    short* WQT  = (short*)(ws + OFF_WQT);
    short* WQFT = (short*)(ws + OFF_WQFT);

    // zero only the 63 pad rows at the head of each bf16 K/V array
    for (int a = 0; a < 4; ++a)
        hipMemsetAsync(kvB + (size_t)a * ASTRIDE, 0, (size_t)PAD * DM * sizeof(short), stream);

    k_wcvt <<<dim3(1024, 8), dim3(256), 0, stream>>>(Wq_enc, W1f, W2f, Wqf, Wk_enc, Wv_enc,
                                                     W1T, W2T, WQT, WQFT, WKVH, WKVL);
    k_wvt  <<<dim3(32, 2), dim3(256), 0, stream>>>(Wvis, WVH, WVL);
    k_viskv<<<dim3(TFRAMES / 16), dim3(256), 0, stream>>>(lf, WVH, WVL, WKVH, WKVL, kvB);
    k_text <<<dim3(NG), dim3(128), 0, stream>>>(g, Wtxt, Wkf, Wvf, text, kfp, vfp);
    k_frames<<<dim3(TFRAMES / FPB), dim3(512), 0, stream>>>(kvB, text, kfp, vfp, W1T, W2T, WQT, WQFT, out);
}